// Round 1
// baseline (513.492 us; speedup 1.0000x reference)
//
#include <hip/hip_runtime.h>
#include <cstdint>

#define NHEAD 8
#define D1 64      // H1*C1
#define IN_F 128
#define NEG 0.2f
#define NBINS 256  // loss partial-sum bins

__device__ __forceinline__ void fma4(float4& a, float s, const float4& v)
{
    a.x = fmaf(s, v.x, a.x); a.y = fmaf(s, v.y, a.y);
    a.z = fmaf(s, v.z, a.z); a.w = fmaf(s, v.w, a.w);
}

// ---------------- Fused: hist8 (first) & gemm1 (h1 = feat@W1 + att dots) -------
// Round-13: hist was latency-bound (VALUBusy 14%, occ 30%, all pipes idle).
//  - p now comes from the REAL XCD id (s_getreg HW_REG_XCC_ID) instead of
//    blockIdx&7, which only tracks the XCD for the first resident wave. p is
//    packed into rank[e] bits [24..27) so k_fill needn't reproduce the mapping.
//  - 4 edges/thread (int4 loads, 4 atomics in flight) + LDS cut 33.8->17.4 KB
//    (quarter-K gemm tiles) -> 7 blocks/CU instead of 4: ~7x in-flight atomics.
//  - hist blocks get LOW blockIdx so the latency-bound long pole starts first.
// Diagnostic: if WRITE_SIZE stays ~88 MB, agent-scope atomics bypass L2 to the
// coherence point regardless of XCD locality -> counting-sort must be replaced
// (LDS radix) next round.
__global__ __launch_bounds__(256) void k_gemm1_hist(
    const float* __restrict__ feat,
    const float* __restrict__ W1,
    const float* __restrict__ att_s,
    const float* __restrict__ att_d,
    float* __restrict__ h1, float* __restrict__ a_src, float* __restrict__ a_dst,
    const int* __restrict__ dst, int* __restrict__ deg8, int* __restrict__ rank,
    int N, int E, int GH)
{
    __shared__ float Wh[32 * 64];   // [kk][c], 8 KB
    __shared__ float Fh[64 * 36];   // [r][kk], stride 36 (144B = 9x16), 9.2 KB
    const int tid = threadIdx.x;

    if ((int)blockIdx.x < GH) {
        // -------- histogram branch: p = hardware XCD id -----------------------
        int xcd;
        asm volatile("s_getreg_b32 %0, hwreg(HW_REG_XCC_ID)" : "=s"(xcd));
        const int p = xcd & 7;
        const int pofs = p * N;
        const int e0 = blockIdx.x * 1024 + tid * 4;
        if (e0 + 3 < E) {
            int4 d4 = *(const int4*)&dst[e0];
            int r0 = atomicAdd(&deg8[pofs + d4.x], 1);
            int r1 = atomicAdd(&deg8[pofs + d4.y], 1);
            int r2 = atomicAdd(&deg8[pofs + d4.z], 1);
            int r3 = atomicAdd(&deg8[pofs + d4.w], 1);
            int4 r4;
            r4.x = (p << 24) | r0; r4.y = (p << 24) | r1;
            r4.z = (p << 24) | r2; r4.w = (p << 24) | r3;
            *(int4*)&rank[e0] = r4;   // coalesced 16B store
        } else if (e0 < E) {
            for (int e = e0; e < E; ++e)
                rank[e] = (p << 24) | atomicAdd(&deg8[pofs + dst[e]], 1);
        }
        return;
    }

    // -------- gemm1 branch: 64x64 tile, 4x4 register tile, K in 4 quarters ----
    const int tx = tid & 15, ty = tid >> 4;
    const int base = (blockIdx.x - GH) * 64;
    float4 acc0 = {0,0,0,0}, acc1 = {0,0,0,0}, acc2 = {0,0,0,0}, acc3 = {0,0,0,0};

    for (int p = 0; p < 4; ++p) {
        if (p) __syncthreads();
        for (int i = tid; i < 32 * 64; i += 256)
            Wh[i] = W1[p * 2048 + i];
        for (int i = tid; i < 64 * 32; i += 256) {
            int r = i >> 5, kk = i & 31;
            int n = base + r;
            Fh[r * 36 + kk] = (n < N) ? feat[(size_t)n * IN_F + p * 32 + kk] : 0.f;
        }
        __syncthreads();
        const float* wk = &Wh[4 * tx];
        const float* f0 = &Fh[(4 * ty + 0) * 36];
        const float* f1 = &Fh[(4 * ty + 1) * 36];
        const float* f2 = &Fh[(4 * ty + 2) * 36];
        const float* f3 = &Fh[(4 * ty + 3) * 36];
        #pragma unroll
        for (int kk = 0; kk < 32; kk += 4) {
            float4 fa = *(const float4*)&f0[kk];
            float4 fb = *(const float4*)&f1[kk];
            float4 fc = *(const float4*)&f2[kk];
            float4 fd = *(const float4*)&f3[kk];
            float4 w0 = *(const float4*)&wk[(kk + 0) * 64];
            float4 w1 = *(const float4*)&wk[(kk + 1) * 64];
            float4 w2 = *(const float4*)&wk[(kk + 2) * 64];
            float4 w3 = *(const float4*)&wk[(kk + 3) * 64];
            fma4(acc0, fa.x, w0); fma4(acc0, fa.y, w1); fma4(acc0, fa.z, w2); fma4(acc0, fa.w, w3);
            fma4(acc1, fb.x, w0); fma4(acc1, fb.y, w1); fma4(acc1, fb.z, w2); fma4(acc1, fb.w, w3);
            fma4(acc2, fc.x, w0); fma4(acc2, fc.y, w1); fma4(acc2, fc.z, w2); fma4(acc2, fc.w, w3);
            fma4(acc3, fd.x, w0); fma4(acc3, fd.y, w1); fma4(acc3, fd.z, w2); fma4(acc3, fd.w, w3);
        }
    }
    const float4 as4 = *(const float4*)&att_s[4 * tx];
    const float4 ad4 = *(const float4*)&att_d[4 * tx];
    float4 accs[4] = {acc0, acc1, acc2, acc3};
    #pragma unroll
    for (int i = 0; i < 4; ++i) {
        int n = base + 4 * ty + i;
        if (n < N) {
            *(float4*)&h1[(size_t)n * D1 + 4 * tx] = accs[i];
            float ps = accs[i].x * as4.x + accs[i].y * as4.y + accs[i].z * as4.z + accs[i].w * as4.w;
            float pd = accs[i].x * ad4.x + accs[i].y * ad4.y + accs[i].z * ad4.z + accs[i].w * ad4.w;
            ps += __shfl_xor(ps, 1);
            pd += __shfl_xor(pd, 1);
            if ((tx & 1) == 0) {
                a_src[n * NHEAD + (tx >> 1)] = ps;
                a_dst[n * NHEAD + (tx >> 1)] = pd;
            }
        }
    }
}

__device__ __forceinline__ int block_incl_scan(int v, int tid, int* lds4)
{
    int lane = tid & 63, w = tid >> 6;
    #pragma unroll
    for (int off = 1; off < 64; off <<= 1) {
        int t = __shfl_up(v, off);
        if (lane >= off) v += t;
    }
    if (lane == 63) lds4[w] = v;
    __syncthreads();
    int add = 0;
    #pragma unroll
    for (int i = 0; i < 4; ++i)
        if (i < w) add += lds4[i];
    __syncthreads();
    return v + add;
}

// scan1 with reduce8 folded in: deg = sum_p deg8, base8 = per-p exclusive bases.
__global__ __launch_bounds__(256) void k_scan1r(
    const int* __restrict__ deg8, int* __restrict__ base8, int* __restrict__ deg,
    int* __restrict__ locx, int* __restrict__ bsum, double* __restrict__ bins, int N)
{
    __shared__ int lds4[4];
    if (blockIdx.x == 0) bins[threadIdx.x] = 0.0;   // fold bins zeroing here
    int i = blockIdx.x * 256 + threadIdx.x;
    int v = 0;
    if (i < N) {
        int b = 0;
        #pragma unroll
        for (int p = 0; p < 8; ++p) {
            base8[p * N + i] = b;
            b += deg8[p * N + i];
        }
        deg[i] = b;
        v = b;
    }
    int incl = block_incl_scan(v, threadIdx.x, lds4);
    if (i < N) locx[i] = incl - v;
    if (threadIdx.x == 255) bsum[blockIdx.x] = incl;
}

__global__ __launch_bounds__(256) void k_scan2(int* __restrict__ bsum, int nblk)
{
    __shared__ int lds4[4];
    __shared__ int carry;
    if (threadIdx.x == 0) carry = 0;
    __syncthreads();
    for (int base = 0; base < nblk; base += 256) {
        int i = base + threadIdx.x;
        int v = (i < nblk) ? bsum[i] : 0;
        int incl = block_incl_scan(v, threadIdx.x, lds4);
        int c = carry;
        __syncthreads();
        if (i < nblk) bsum[i] = incl - v + c;
        if (threadIdx.x == 255) carry = c + incl;
        __syncthreads();
    }
}

// offs computed inline: locx[d] + bsum[d>>8].  p decoded from rank high bits.
// atomicExch: plain scattered 4B stores write through at 64B/op; exch stays in L2.
// 4 edges/thread: int4 loads + 4 independent gather/exch chains in flight.
__global__ __launch_bounds__(256) void k_fill(
    const int* __restrict__ src, const int* __restrict__ dst,
    const int* __restrict__ rank, const int* __restrict__ locx,
    const int* __restrict__ bsum, const int* __restrict__ base8,
    int* __restrict__ srcs, int E, int N)
{
    const int e0 = blockIdx.x * 1024 + threadIdx.x * 4;
    if (e0 + 3 < E) {
        int4 s4 = *(const int4*)&src[e0];
        int4 d4 = *(const int4*)&dst[e0];
        int4 r4 = *(const int4*)&rank[e0];
        int slot0 = locx[d4.x] + bsum[d4.x >> 8] + base8[(r4.x >> 24) * N + d4.x] + (r4.x & 0xFFFFFF);
        int slot1 = locx[d4.y] + bsum[d4.y >> 8] + base8[(r4.y >> 24) * N + d4.y] + (r4.y & 0xFFFFFF);
        int slot2 = locx[d4.z] + bsum[d4.z >> 8] + base8[(r4.z >> 24) * N + d4.z] + (r4.z & 0xFFFFFF);
        int slot3 = locx[d4.w] + bsum[d4.w >> 8] + base8[(r4.w >> 24) * N + d4.w] + (r4.w & 0xFFFFFF);
        (void)atomicExch(&srcs[slot0], s4.x);
        (void)atomicExch(&srcs[slot1], s4.y);
        (void)atomicExch(&srcs[slot2], s4.z);
        (void)atomicExch(&srcs[slot3], s4.w);
    } else if (e0 < E) {
        for (int e = e0; e < E; ++e) {
            int rv = rank[e];
            int d = dst[e];
            int slot = locx[d] + bsum[d >> 8] + base8[(rv >> 24) * N + d] + (rv & 0xFFFFFF);
            (void)atomicExch(&srcs[slot], src[e]);
        }
    }
}

// ---------------- Layer-1 aggregation, 2-deep software pipeline ----------------
__global__ __launch_bounds__(256) void k_agg1(
    const int* __restrict__ deg, const int* __restrict__ locx,
    const int* __restrict__ bsum, const int* __restrict__ srcs,
    const float* __restrict__ a_s, const float* __restrict__ a_d,
    const float* __restrict__ h1, const float* __restrict__ b1,
    float* __restrict__ x, int N)
{
    const int tid = threadIdx.x, w = tid >> 6, j = tid & 63;
    const int c = j & 7, hh = j >> 3;      // producer: edge-slot c, head hh
    const int n = blockIdx.x * 4 + w;
    if (n >= N) return;
    const int rlen = deg[n];
    const int row = locx[n] + bsum[n >> 8];
    const float ad = a_d[n * NHEAD + hh];
    float acc0 = 0.f, acc1 = 0.f, den = 0.f;
    int m = rlen < 8 ? rlen : 8;
    int myS   = (c < m) ? srcs[row + c] : 0;
    float av  = (c < m) ? a_s[myS * NHEAD + hh] : 0.f;
    for (int base = 0; base < rlen; base += 8) {
        int mn = rlen - base - 8; if (mn > 8) mn = 8;
        int   myS_n = (c < mn) ? srcs[row + base + 8 + c] : 0;
        float av_n  = (c < mn) ? a_s[myS_n * NHEAD + hh] : 0.f;
        float ex = 0.f;
        if (c < m) {
            float v = av + ad;
            v = v > 0.f ? v : NEG * v;
            ex = expf(v);
        }
        float ds = ex;                      // per-head denom: aligned 8-lane group reduce
        ds += __shfl_xor(ds, 1);
        ds += __shfl_xor(ds, 2);
        ds += __shfl_xor(ds, 4);
        den += ds;
        if (m == 8) {
            int   s8[8]; float e8[8], l8[8];
            #pragma unroll
            for (int k = 0; k < 8; ++k) {
                s8[k] = __builtin_amdgcn_readlane(myS, k);
                e8[k] = __shfl(ex, (j & 0x38) | k);
            }
            #pragma unroll
            for (int k = 0; k < 8; ++k)
                l8[k] = h1[(size_t)s8[k] * D1 + j];   // 8 loads in flight
            #pragma unroll
            for (int k = 0; k < 8; ++k) {
                if (k & 1) acc1 = fmaf(e8[k], l8[k], acc1);
                else       acc0 = fmaf(e8[k], l8[k], acc0);
            }
        } else {
            for (int k = 0; k < m; ++k) {
                int s = __shfl(myS, k);
                float exk = __shfl(ex, (j & 0x38) | k);
                if (k & 1) acc1 = fmaf(exk, h1[(size_t)s * D1 + j], acc1);
                else       acc0 = fmaf(exk, h1[(size_t)s * D1 + j], acc0);
            }
        }
        myS = myS_n; av = av_n; m = mn > 0 ? mn : 0;
    }
    float o = (acc0 + acc1) / den + b1[j];
    x[(size_t)n * D1 + j] = o > 0.f ? o : expm1f(o);
}

// ---------------- Kernel D: h2 = x @ W2, a_src2/a_dst2 (4x4 register tile) ----------------
__global__ __launch_bounds__(256) void k_gemm2(
    const float* __restrict__ x,
    const float* __restrict__ W2,
    const float* __restrict__ att_s,
    const float* __restrict__ att_d,
    float* __restrict__ h2, float* __restrict__ a_src, float* __restrict__ a_dst,
    int N)
{
    __shared__ float Wh[64 * 64];
    __shared__ float Fh[64 * 68];
    const int tid = threadIdx.x;
    const int tx = tid & 15, ty = tid >> 4;
    const int base = blockIdx.x * 64;
    for (int i = tid; i < 64 * 64; i += 256)
        Wh[i] = W2[i];
    for (int i = tid; i < 64 * 64; i += 256) {
        int r = i >> 6, kk = i & 63;
        int n = base + r;
        Fh[r * 68 + kk] = (n < N) ? x[(size_t)n * 64 + kk] : 0.f;
    }
    __syncthreads();
    float4 acc0 = {0,0,0,0}, acc1 = {0,0,0,0}, acc2 = {0,0,0,0}, acc3 = {0,0,0,0};
    const float* wk = &Wh[4 * tx];
    const float* f0 = &Fh[(4 * ty + 0) * 68];
    const float* f1 = &Fh[(4 * ty + 1) * 68];
    const float* f2 = &Fh[(4 * ty + 2) * 68];
    const float* f3 = &Fh[(4 * ty + 3) * 68];
    #pragma unroll 4
    for (int kk = 0; kk < 64; kk += 4) {
        float4 fa = *(const float4*)&f0[kk];
        float4 fb = *(const float4*)&f1[kk];
        float4 fc = *(const float4*)&f2[kk];
        float4 fd = *(const float4*)&f3[kk];
        float4 w0 = *(const float4*)&wk[(kk + 0) * 64];
        float4 w1 = *(const float4*)&wk[(kk + 1) * 64];
        float4 w2 = *(const float4*)&wk[(kk + 2) * 64];
        float4 w3 = *(const float4*)&wk[(kk + 3) * 64];
        fma4(acc0, fa.x, w0); fma4(acc0, fa.y, w1); fma4(acc0, fa.z, w2); fma4(acc0, fa.w, w3);
        fma4(acc1, fb.x, w0); fma4(acc1, fb.y, w1); fma4(acc1, fb.z, w2); fma4(acc1, fb.w, w3);
        fma4(acc2, fc.x, w0); fma4(acc2, fc.y, w1); fma4(acc2, fc.z, w2); fma4(acc2, fc.w, w3);
        fma4(acc3, fd.x, w0); fma4(acc3, fd.y, w1); fma4(acc3, fd.z, w2); fma4(acc3, fd.w, w3);
    }
    const float4 as4 = *(const float4*)&att_s[4 * tx];
    const float4 ad4 = *(const float4*)&att_d[4 * tx];
    float4 accs[4] = {acc0, acc1, acc2, acc3};
    #pragma unroll
    for (int i = 0; i < 4; ++i) {
        int n = base + 4 * ty + i;
        if (n < N) {
            *(float4*)&h2[(size_t)n * 64 + 4 * tx] = accs[i];
            float ps = accs[i].x * as4.x + accs[i].y * as4.y + accs[i].z * as4.z + accs[i].w * as4.w;
            float pd = accs[i].x * ad4.x + accs[i].y * ad4.y + accs[i].z * ad4.z + accs[i].w * ad4.w;
            ps += __shfl_xor(ps, 1); pd += __shfl_xor(pd, 1);
            ps += __shfl_xor(ps, 2); pd += __shfl_xor(pd, 2);
            ps += __shfl_xor(ps, 4); pd += __shfl_xor(pd, 4);
            ps += __shfl_xor(ps, 8); pd += __shfl_xor(pd, 8);
            if (tx == 0) { a_src[n] = ps; a_dst[n] = pd; }
        }
    }
}

// ---------------- Layer-2 aggregation + bias + log-softmax + argmax + NLL ----------------
__global__ __launch_bounds__(256) void k_agg2(
    const int* __restrict__ deg, const int* __restrict__ locx,
    const int* __restrict__ bsum, const int* __restrict__ srcs,
    const float* __restrict__ a_s, const float* __restrict__ a_d,
    const float* __restrict__ h2, const float* __restrict__ b2,
    const int* __restrict__ label,
    float* __restrict__ dout, double* __restrict__ bins, int N)
{
    __shared__ float snll[4];
    const int tid = threadIdx.x, w = tid >> 6, j = tid & 63;
    const int t = j & 15, q = j >> 4;
    const int n = blockIdx.x * 4 + w;
    if (j == 0) snll[w] = 0.f;
    if (n < N) {
        const int rlen = deg[n];
        const int row = locx[n] + bsum[n >> 8];
        const float ad = a_d[n];
        float4 acc = {0.f, 0.f, 0.f, 0.f};
        float den = 0.f;
        for (int base = 0; base < rlen; base += 64) {
            int m = rlen - base; if (m > 64) m = 64;
            int myS = 0; float ex = 0.f;
            if (j < m) {
                myS = srcs[row + base + j];
                float v = a_s[myS] + ad;
                v = v > 0.f ? v : NEG * v;
                ex = expf(v);
            }
            float ds = ex;
            #pragma unroll
            for (int off = 1; off < 64; off <<= 1) ds += __shfl_xor(ds, off);
            den += ds;
            int eb = 0;
            for (; eb + 16 <= m; eb += 16) {           // 4 gathers in flight
                int s4[4]; float e4[4]; float4 l4[4];
                #pragma unroll
                for (int ii = 0; ii < 4; ++ii) {
                    int e = eb + 4 * ii + q;
                    s4[ii] = __shfl(myS, e);
                    e4[ii] = __shfl(ex, e);
                }
                #pragma unroll
                for (int ii = 0; ii < 4; ++ii)
                    l4[ii] = *(const float4*)&h2[(size_t)s4[ii] * 64 + 4 * t];
                #pragma unroll
                for (int ii = 0; ii < 4; ++ii)
                    fma4(acc, e4[ii], l4[ii]);
            }
            for (; eb + 4 <= m; eb += 4) {
                int e = eb + q;
                int sk = __shfl(myS, e);
                float ek = __shfl(ex, e);
                float4 lk = *(const float4*)&h2[(size_t)sk * 64 + 4 * t];
                fma4(acc, ek, lk);
            }
            for (int k = eb; k < m; ++k) {
                int sk = __shfl(myS, k);
                float ek = __shfl(ex, k);
                if (q == (k & 3)) {
                    float4 lk = *(const float4*)&h2[(size_t)sk * 64 + 4 * t];
                    fma4(acc, ek, lk);
                }
            }
        }
        acc.x += __shfl_xor(acc.x, 16); acc.y += __shfl_xor(acc.y, 16);
        acc.z += __shfl_xor(acc.z, 16); acc.w += __shfl_xor(acc.w, 16);
        acc.x += __shfl_xor(acc.x, 32); acc.y += __shfl_xor(acc.y, 32);
        acc.z += __shfl_xor(acc.z, 32); acc.w += __shfl_xor(acc.w, 32);
        float4 b = *(const float4*)&b2[4 * t];
        float4 sc;
        sc.x = acc.x / den + b.x; sc.y = acc.y / den + b.y;
        sc.z = acc.z / den + b.z; sc.w = acc.w / den + b.w;
        float mv = sc.x; int mi = 4 * t;
        if (sc.y > mv) { mv = sc.y; mi = 4 * t + 1; }
        if (sc.z > mv) { mv = sc.z; mi = 4 * t + 2; }
        if (sc.w > mv) { mv = sc.w; mi = 4 * t + 3; }
        #pragma unroll
        for (int off = 1; off < 16; off <<= 1) {
            float ov = __shfl_xor(mv, off);
            int oi = __shfl_xor(mi, off);
            if (ov > mv || (ov == mv && oi < mi)) { mv = ov; mi = oi; }
        }
        float se = expf(sc.x - mv) + expf(sc.y - mv) + expf(sc.z - mv) + expf(sc.w - mv);
        #pragma unroll
        for (int off = 1; off < 16; off <<= 1) se += __shfl_xor(se, off);
        int lab = label[n];
        int comp = lab & 3;
        float cl = comp == 0 ? sc.x : comp == 1 ? sc.y : comp == 2 ? sc.z : sc.w;
        float sl = __shfl(cl, (j & 0x30) | (lab >> 2));
        if (j == 0) {
            snll[w] = mv + logf(se) - sl;
            dout[1 + n] = (float)mi;
            dout[1 + (size_t)N + n] = (float)lab;
        }
    }
    __syncthreads();
    if (tid == 0) {
        double bsum4 = (double)snll[0] + (double)snll[1]
                     + (double)snll[2] + (double)snll[3];
        atomicAdd(&bins[blockIdx.x & (NBINS - 1)], bsum4);
    }
}

// Single block of 256: reduce NBINS doubles -> loss
__global__ __launch_bounds__(256) void k_loss(
    const double* __restrict__ bins, float* __restrict__ dout, int N)
{
    __shared__ double sw[4];
    const int tid = threadIdx.x;
    double v = bins[tid];
    #pragma unroll
    for (int off = 1; off < 64; off <<= 1) v += __shfl_xor(v, off);
    if ((tid & 63) == 0) sw[tid >> 6] = v;
    __syncthreads();
    if (tid == 0)
        dout[0] = (float)((sw[0] + sw[1] + sw[2] + sw[3]) / (double)N);
}

extern "C" void kernel_launch(void* const* d_in, const int* in_sizes, int n_in,
                              void* d_out, int out_size, void* d_ws, size_t ws_size,
                              hipStream_t stream)
{
    const float* feat   = (const float*)d_in[1];
    const int*   edge   = (const int*)d_in[2];
    const int*   label  = (const int*)d_in[4];
    const float* W1     = (const float*)d_in[5];
    const float* att_s1 = (const float*)d_in[6];
    const float* att_d1 = (const float*)d_in[7];
    const float* b1     = (const float*)d_in[8];
    const float* W2     = (const float*)d_in[9];
    const float* att_s2 = (const float*)d_in[10];
    const float* att_d2 = (const float*)d_in[11];
    const float* b2     = (const float*)d_in[12];

    const int N = in_sizes[0];
    const int E = in_sizes[2] / 2;
    const int* src = edge;
    const int* dst = edge + E;

    // workspace layout:
    float* bufA = (float*)d_ws;               // N*64: h1 / h2 (no aliases)
    float* bufB = bufA + (size_t)N * 64;      // N*64: x; aliases rank[E]+deg8[8N]+base8[8N]
    float* a_s1 = bufB + (size_t)N * 64;      // N*8 (layer2: a_s2=[0..N), a_d2=[N..2N))
    float* a_d1 = a_s1 + (size_t)N * 8;       // N*8
    int*   deg  = (int*)(a_d1 + (size_t)N * 8); // N
    int*   locx = deg + N;                    // N
    int*   srcs = locx + N;                   // E
    int*   bsum = srcs + E;                   // nblk (scan scratch)
    double* bins = (double*)(((uintptr_t)(bsum + ((N + 255) / 256) + 1) + 7) & ~(uintptr_t)7);

    // Aliases in bufB — all dead before k_agg1 writes x:
    int* rank  = (int*)bufB;                  // E
    int* deg8  = rank + E;                    // 8N
    int* base8 = deg8 + (size_t)8 * N;        // 8N

    float* a_s2 = a_s1;
    float* a_d2 = a_s1 + N;

    float* out = (float*)d_out;

    const int nblk   = (N + 255) / 256;
    const int egrid4 = (E + 1023) / 1024;     // 4 edges/thread
    const int G1     = (N + 63) / 64;
    const int GH     = egrid4;                // hist blocks come FIRST

    hipMemsetAsync(deg8, 0, (size_t)8 * N * sizeof(int), stream);

    // hist (latency-bound long pole, dispatched first) overlapped with gemm1.
    k_gemm1_hist<<<GH + G1, 256, 0, stream>>>(feat, W1, att_s1, att_d1,
                                              bufA, a_s1, a_d1,
                                              dst, deg8, rank, N, E, GH);
    k_scan1r<<<nblk, 256, 0, stream>>>(deg8, base8, deg, locx, bsum, bins, N);
    k_scan2 <<<1, 256, 0, stream>>>(bsum, nblk);
    k_fill  <<<egrid4, 256, 0, stream>>>(src, dst, rank, locx, bsum, base8, srcs, E, N);

    k_agg1 <<<(N + 3) / 4, 256, 0, stream>>>(deg, locx, bsum, srcs, a_s1, a_d1,
                                             bufA, b1, bufB, N);
    k_gemm2<<<G1, 256, 0, stream>>>(bufB, W2, att_s2, att_d2, bufA, a_s2, a_d2, N);
    k_agg2 <<<(N + 3) / 4, 256, 0, stream>>>(deg, locx, bsum, srcs, a_s2, a_d2,
                                             bufA, b2, label, out, bins, N);
    k_loss <<<1, 256, 0, stream>>>(bins, out, N);
}

// Round 2
// 428.420 us; speedup vs baseline: 1.1986x; 1.1986x over previous
//
#include <hip/hip_runtime.h>
#include <cstdint>

#define NHEAD 8
#define D1 64      // H1*C1
#define IN_F 128
#define NEG 0.2f
#define NBINS 256  // loss partial-sum bins
#define BINS 1024  // dst buckets of 128 nodes each (bin = dst>>7); valid for N <= 131072
#define BSH 7
#define CHUNK 8192 // edges per hist/scatter block (32/thread)

__device__ __forceinline__ void fma4(float4& a, float s, const float4& v)
{
    a.x = fmaf(s, v.x, a.x); a.y = fmaf(s, v.y, a.y);
    a.z = fmaf(s, v.z, a.z); a.w = fmaf(s, v.w, a.w);
}

// ---------------- Fused: bucket-hist (first) & gemm1 ---------------------------
// Round-14: WRITE_SIZE stayed 89 MB with true-XCD partitioning -> device atomics
// resolve at the memory-side coherence point (~32B writeback each, ~16G/s wall).
// Fix: keep per-edge atomics in LDS. Per block: LDS hist over 8192 edges, then
// only ~782 global adds (no-return) into padded bucket totals. Per-block hists
// are saved to bh[] so the scatter pass needn't recount.
__global__ __launch_bounds__(256) void k_gemm1_hist(
    const float* __restrict__ feat,
    const float* __restrict__ W1,
    const float* __restrict__ att_s,
    const float* __restrict__ att_d,
    float* __restrict__ h1, float* __restrict__ a_src, float* __restrict__ a_dst,
    const int* __restrict__ dst, int* __restrict__ btot, int* __restrict__ bh,
    int N, int E, int GH)
{
    __shared__ float Wh[32 * 64];   // gemm: [kk][c], 8 KB (hist reuses as int hist[1024])
    __shared__ float Fh[64 * 36];   // gemm: [r][kk], stride 36, 9.2 KB
    const int tid = threadIdx.x;

    if ((int)blockIdx.x < GH) {
        // -------- histogram branch: all per-edge atomics in LDS ---------------
        int* hist = (int*)Wh;
        for (int b = tid; b < BINS; b += 256) hist[b] = 0;
        __syncthreads();
        const int e0 = blockIdx.x * CHUNK;
        #pragma unroll
        for (int r = 0; r < 8; ++r) {
            int e = e0 + r * 1024 + tid * 4;
            if (e + 3 < E) {
                int4 d4 = *(const int4*)&dst[e];
                atomicAdd(&hist[d4.x >> BSH], 1);
                atomicAdd(&hist[d4.y >> BSH], 1);
                atomicAdd(&hist[d4.z >> BSH], 1);
                atomicAdd(&hist[d4.w >> BSH], 1);
            } else {
                for (int k = e; k < E && k < e + 4; ++k)
                    atomicAdd(&hist[dst[k] >> BSH], 1);
            }
        }
        __syncthreads();
        for (int b = tid; b < BINS; b += 256) {
            int c = hist[b];
            bh[(size_t)blockIdx.x * BINS + b] = c;      // coalesced 4 KB store
            if (c) atomicAdd(&btot[b * 16], c);         // no-return, padded line
        }
        return;
    }

    // -------- gemm1 branch: 64x64 tile, 4x4 register tile, K in 4 quarters ----
    const int tx = tid & 15, ty = tid >> 4;
    const int base = (blockIdx.x - GH) * 64;
    float4 acc0 = {0,0,0,0}, acc1 = {0,0,0,0}, acc2 = {0,0,0,0}, acc3 = {0,0,0,0};

    for (int p = 0; p < 4; ++p) {
        if (p) __syncthreads();
        for (int i = tid; i < 32 * 64; i += 256)
            Wh[i] = W1[p * 2048 + i];
        for (int i = tid; i < 64 * 32; i += 256) {
            int r = i >> 5, kk = i & 31;
            int n = base + r;
            Fh[r * 36 + kk] = (n < N) ? feat[(size_t)n * IN_F + p * 32 + kk] : 0.f;
        }
        __syncthreads();
        const float* wk = &Wh[4 * tx];
        const float* f0 = &Fh[(4 * ty + 0) * 36];
        const float* f1 = &Fh[(4 * ty + 1) * 36];
        const float* f2 = &Fh[(4 * ty + 2) * 36];
        const float* f3 = &Fh[(4 * ty + 3) * 36];
        #pragma unroll
        for (int kk = 0; kk < 32; kk += 4) {
            float4 fa = *(const float4*)&f0[kk];
            float4 fb = *(const float4*)&f1[kk];
            float4 fc = *(const float4*)&f2[kk];
            float4 fd = *(const float4*)&f3[kk];
            float4 w0 = *(const float4*)&wk[(kk + 0) * 64];
            float4 w1 = *(const float4*)&wk[(kk + 1) * 64];
            float4 w2 = *(const float4*)&wk[(kk + 2) * 64];
            float4 w3 = *(const float4*)&wk[(kk + 3) * 64];
            fma4(acc0, fa.x, w0); fma4(acc0, fa.y, w1); fma4(acc0, fa.z, w2); fma4(acc0, fa.w, w3);
            fma4(acc1, fb.x, w0); fma4(acc1, fb.y, w1); fma4(acc1, fb.z, w2); fma4(acc1, fb.w, w3);
            fma4(acc2, fc.x, w0); fma4(acc2, fc.y, w1); fma4(acc2, fc.z, w2); fma4(acc2, fc.w, w3);
            fma4(acc3, fd.x, w0); fma4(acc3, fd.y, w1); fma4(acc3, fd.z, w2); fma4(acc3, fd.w, w3);
        }
    }
    const float4 as4 = *(const float4*)&att_s[4 * tx];
    const float4 ad4 = *(const float4*)&att_d[4 * tx];
    float4 accs[4] = {acc0, acc1, acc2, acc3};
    #pragma unroll
    for (int i = 0; i < 4; ++i) {
        int n = base + 4 * ty + i;
        if (n < N) {
            *(float4*)&h1[(size_t)n * D1 + 4 * tx] = accs[i];
            float ps = accs[i].x * as4.x + accs[i].y * as4.y + accs[i].z * as4.z + accs[i].w * as4.w;
            float pd = accs[i].x * ad4.x + accs[i].y * ad4.y + accs[i].z * ad4.z + accs[i].w * ad4.w;
            ps += __shfl_xor(ps, 1);
            pd += __shfl_xor(pd, 1);
            if ((tx & 1) == 0) {
                a_src[n * NHEAD + (tx >> 1)] = ps;
                a_dst[n * NHEAD + (tx >> 1)] = pd;
            }
        }
    }
}

__device__ __forceinline__ int block_incl_scan(int v, int tid, int* lds4)
{
    int lane = tid & 63, w = tid >> 6;
    #pragma unroll
    for (int off = 1; off < 64; off <<= 1) {
        int t = __shfl_up(v, off);
        if (lane >= off) v += t;
    }
    if (lane == 63) lds4[w] = v;
    __syncthreads();
    int add = 0;
    #pragma unroll
    for (int i = 0; i < 4; ++i)
        if (i < w) add += lds4[i];
    __syncthreads();
    return v + add;
}

// Scan the 1024 bucket totals -> bucket bases; init the padded global cursors;
// zero the loss bins (folded here).
__global__ __launch_bounds__(256) void k_bscan(
    const int* __restrict__ btot, int* __restrict__ bbase, int* __restrict__ gcur,
    double* __restrict__ bins)
{
    __shared__ int lds4[4];
    const int tid = threadIdx.x;
    bins[tid] = 0.0;
    int c0 = btot[(4 * tid + 0) * 16];
    int c1 = btot[(4 * tid + 1) * 16];
    int c2 = btot[(4 * tid + 2) * 16];
    int c3 = btot[(4 * tid + 3) * 16];
    int v = c0 + c1 + c2 + c3;
    int incl = block_incl_scan(v, tid, lds4);
    int b0 = incl - v, b1 = b0 + c0, b2 = b1 + c1, b3 = b2 + c2;
    bbase[4 * tid + 0] = b0; gcur[(4 * tid + 0) * 16] = b0;
    bbase[4 * tid + 1] = b1; gcur[(4 * tid + 1) * 16] = b1;
    bbase[4 * tid + 2] = b2; gcur[(4 * tid + 2) * 16] = b2;
    bbase[4 * tid + 3] = b3; gcur[(4 * tid + 3) * 16] = b3;
}

// Scatter edges into their dst-bucket. Per block: ~782 with-return global adds
// (one per non-empty bucket, padded cursor lines) to reserve space; per-edge
// ranks come from LDS cursors. Packed entry: (dst&127)<<17 | src  (N < 2^17).
__global__ __launch_bounds__(256) void k_scatter(
    const int* __restrict__ src, const int* __restrict__ dst,
    const int* __restrict__ bh, int* __restrict__ gcur,
    int* __restrict__ bucketed, int E)
{
    __shared__ int base[BINS], cur[BINS];
    const int tid = threadIdx.x;
    for (int b = tid; b < BINS; b += 256) {
        cur[b] = 0;
        int c = bh[(size_t)blockIdx.x * BINS + b];
        if (c) base[b] = atomicAdd(&gcur[b * 16], c);
    }
    __syncthreads();
    const int e0 = blockIdx.x * CHUNK;
    #pragma unroll
    for (int r = 0; r < 8; ++r) {
        int e = e0 + r * 1024 + tid * 4;
        if (e + 3 < E) {
            int4 d4 = *(const int4*)&dst[e];
            int4 s4 = *(const int4*)&src[e];
            int bx, rx;
            bx = d4.x >> BSH; rx = atomicAdd(&cur[bx], 1); bucketed[base[bx] + rx] = ((d4.x & 127) << 17) | s4.x;
            bx = d4.y >> BSH; rx = atomicAdd(&cur[bx], 1); bucketed[base[bx] + rx] = ((d4.y & 127) << 17) | s4.y;
            bx = d4.z >> BSH; rx = atomicAdd(&cur[bx], 1); bucketed[base[bx] + rx] = ((d4.z & 127) << 17) | s4.z;
            bx = d4.w >> BSH; rx = atomicAdd(&cur[bx], 1); bucketed[base[bx] + rx] = ((d4.w & 127) << 17) | s4.w;
        } else {
            for (int k = e; k < E && k < e + 4; ++k) {
                int d = dst[k];
                int bx = d >> BSH;
                int rx = atomicAdd(&cur[bx], 1);
                bucketed[base[bx] + rx] = ((d & 127) << 17) | src[k];
            }
        }
    }
}

// One block per bucket: count 128 local nodes in LDS, scan in LDS, emit
// deg/rowstart directly (rowstart = bucket_base + local_base -> no global scan),
// then scatter the bucket into final CSR positions (contiguous ~9 KB region).
__global__ __launch_bounds__(256) void k_seg(
    const int* __restrict__ btot, const int* __restrict__ bbase,
    const int* __restrict__ bucketed,
    int* __restrict__ deg, int* __restrict__ rowstart, int* __restrict__ srcs, int N)
{
    __shared__ int cnt[128], cur[128], lb[128];
    const int tid = threadIdx.x;
    const int b = blockIdx.x;
    const int gs = bbase[b];
    const int sz = btot[b * 16];
    if (tid < 128) { cnt[tid] = 0; cur[tid] = 0; }
    __syncthreads();
    for (int i = tid; i < sz; i += 256)
        atomicAdd(&cnt[bucketed[gs + i] >> 17], 1);
    __syncthreads();
    if (tid < 128) lb[tid] = cnt[tid];
    __syncthreads();
    #pragma unroll
    for (int off = 1; off < 128; off <<= 1) {
        int t = 0;
        if (tid < 128 && tid >= off) t = lb[tid - off];
        __syncthreads();
        if (tid < 128 && tid >= off) lb[tid] += t;
        __syncthreads();
    }
    if (tid < 128) {
        int ex = lb[tid] - cnt[tid];   // exclusive local base
        lb[tid] = ex;
        int d = b * 128 + tid;
        if (d < N) { deg[d] = cnt[tid]; rowstart[d] = gs + ex; }
    }
    __syncthreads();
    for (int i = tid; i < sz; i += 256) {
        int v = bucketed[gs + i];
        int d7 = v >> 17;
        int r = atomicAdd(&cur[d7], 1);
        srcs[gs + lb[d7] + r] = v & 0x1FFFF;
    }
}

// ---------------- Layer-1 aggregation, 2-deep software pipeline ----------------
__global__ __launch_bounds__(256) void k_agg1(
    const int* __restrict__ deg, const int* __restrict__ rowstart,
    const int* __restrict__ srcs,
    const float* __restrict__ a_s, const float* __restrict__ a_d,
    const float* __restrict__ h1, const float* __restrict__ b1,
    float* __restrict__ x, int N)
{
    const int tid = threadIdx.x, w = tid >> 6, j = tid & 63;
    const int c = j & 7, hh = j >> 3;      // producer: edge-slot c, head hh
    const int n = blockIdx.x * 4 + w;
    if (n >= N) return;
    const int rlen = deg[n];
    const int row = rowstart[n];
    const float ad = a_d[n * NHEAD + hh];
    float acc0 = 0.f, acc1 = 0.f, den = 0.f;
    int m = rlen < 8 ? rlen : 8;
    int myS   = (c < m) ? srcs[row + c] : 0;
    float av  = (c < m) ? a_s[myS * NHEAD + hh] : 0.f;
    for (int base = 0; base < rlen; base += 8) {
        int mn = rlen - base - 8; if (mn > 8) mn = 8;
        int   myS_n = (c < mn) ? srcs[row + base + 8 + c] : 0;
        float av_n  = (c < mn) ? a_s[myS_n * NHEAD + hh] : 0.f;
        float ex = 0.f;
        if (c < m) {
            float v = av + ad;
            v = v > 0.f ? v : NEG * v;
            ex = expf(v);
        }
        float ds = ex;                      // per-head denom: aligned 8-lane group reduce
        ds += __shfl_xor(ds, 1);
        ds += __shfl_xor(ds, 2);
        ds += __shfl_xor(ds, 4);
        den += ds;
        if (m == 8) {
            int   s8[8]; float e8[8], l8[8];
            #pragma unroll
            for (int k = 0; k < 8; ++k) {
                s8[k] = __builtin_amdgcn_readlane(myS, k);
                e8[k] = __shfl(ex, (j & 0x38) | k);
            }
            #pragma unroll
            for (int k = 0; k < 8; ++k)
                l8[k] = h1[(size_t)s8[k] * D1 + j];   // 8 loads in flight
            #pragma unroll
            for (int k = 0; k < 8; ++k) {
                if (k & 1) acc1 = fmaf(e8[k], l8[k], acc1);
                else       acc0 = fmaf(e8[k], l8[k], acc0);
            }
        } else {
            for (int k = 0; k < m; ++k) {
                int s = __shfl(myS, k);
                float exk = __shfl(ex, (j & 0x38) | k);
                if (k & 1) acc1 = fmaf(exk, h1[(size_t)s * D1 + j], acc1);
                else       acc0 = fmaf(exk, h1[(size_t)s * D1 + j], acc0);
            }
        }
        myS = myS_n; av = av_n; m = mn > 0 ? mn : 0;
    }
    float o = (acc0 + acc1) / den + b1[j];
    x[(size_t)n * D1 + j] = o > 0.f ? o : expm1f(o);
}

// ---------------- Kernel D: h2 = x @ W2, a_src2/a_dst2 (4x4 register tile) ----------------
__global__ __launch_bounds__(256) void k_gemm2(
    const float* __restrict__ x,
    const float* __restrict__ W2,
    const float* __restrict__ att_s,
    const float* __restrict__ att_d,
    float* __restrict__ h2, float* __restrict__ a_src, float* __restrict__ a_dst,
    int N)
{
    __shared__ float Wh[64 * 64];
    __shared__ float Fh[64 * 68];
    const int tid = threadIdx.x;
    const int tx = tid & 15, ty = tid >> 4;
    const int base = blockIdx.x * 64;
    for (int i = tid; i < 64 * 64; i += 256)
        Wh[i] = W2[i];
    for (int i = tid; i < 64 * 64; i += 256) {
        int r = i >> 6, kk = i & 63;
        int n = base + r;
        Fh[r * 68 + kk] = (n < N) ? x[(size_t)n * 64 + kk] : 0.f;
    }
    __syncthreads();
    float4 acc0 = {0,0,0,0}, acc1 = {0,0,0,0}, acc2 = {0,0,0,0}, acc3 = {0,0,0,0};
    const float* wk = &Wh[4 * tx];
    const float* f0 = &Fh[(4 * ty + 0) * 68];
    const float* f1 = &Fh[(4 * ty + 1) * 68];
    const float* f2 = &Fh[(4 * ty + 2) * 68];
    const float* f3 = &Fh[(4 * ty + 3) * 68];
    #pragma unroll 4
    for (int kk = 0; kk < 64; kk += 4) {
        float4 fa = *(const float4*)&f0[kk];
        float4 fb = *(const float4*)&f1[kk];
        float4 fc = *(const float4*)&f2[kk];
        float4 fd = *(const float4*)&f3[kk];
        float4 w0 = *(const float4*)&wk[(kk + 0) * 64];
        float4 w1 = *(const float4*)&wk[(kk + 1) * 64];
        float4 w2 = *(const float4*)&wk[(kk + 2) * 64];
        float4 w3 = *(const float4*)&wk[(kk + 3) * 64];
        fma4(acc0, fa.x, w0); fma4(acc0, fa.y, w1); fma4(acc0, fa.z, w2); fma4(acc0, fa.w, w3);
        fma4(acc1, fb.x, w0); fma4(acc1, fb.y, w1); fma4(acc1, fb.z, w2); fma4(acc1, fb.w, w3);
        fma4(acc2, fc.x, w0); fma4(acc2, fc.y, w1); fma4(acc2, fc.z, w2); fma4(acc2, fc.w, w3);
        fma4(acc3, fd.x, w0); fma4(acc3, fd.y, w1); fma4(acc3, fd.z, w2); fma4(acc3, fd.w, w3);
    }
    const float4 as4 = *(const float4*)&att_s[4 * tx];
    const float4 ad4 = *(const float4*)&att_d[4 * tx];
    float4 accs[4] = {acc0, acc1, acc2, acc3};
    #pragma unroll
    for (int i = 0; i < 4; ++i) {
        int n = base + 4 * ty + i;
        if (n < N) {
            *(float4*)&h2[(size_t)n * 64 + 4 * tx] = accs[i];
            float ps = accs[i].x * as4.x + accs[i].y * as4.y + accs[i].z * as4.z + accs[i].w * as4.w;
            float pd = accs[i].x * ad4.x + accs[i].y * ad4.y + accs[i].z * ad4.z + accs[i].w * ad4.w;
            ps += __shfl_xor(ps, 1); pd += __shfl_xor(pd, 1);
            ps += __shfl_xor(ps, 2); pd += __shfl_xor(pd, 2);
            ps += __shfl_xor(ps, 4); pd += __shfl_xor(pd, 4);
            ps += __shfl_xor(ps, 8); pd += __shfl_xor(pd, 8);
            if (tx == 0) { a_src[n] = ps; a_dst[n] = pd; }
        }
    }
}

// ---------------- Layer-2 aggregation + bias + log-softmax + argmax + NLL ----------------
__global__ __launch_bounds__(256) void k_agg2(
    const int* __restrict__ deg, const int* __restrict__ rowstart,
    const int* __restrict__ srcs,
    const float* __restrict__ a_s, const float* __restrict__ a_d,
    const float* __restrict__ h2, const float* __restrict__ b2,
    const int* __restrict__ label,
    float* __restrict__ dout, double* __restrict__ bins, int N)
{
    __shared__ float snll[4];
    const int tid = threadIdx.x, w = tid >> 6, j = tid & 63;
    const int t = j & 15, q = j >> 4;
    const int n = blockIdx.x * 4 + w;
    if (j == 0) snll[w] = 0.f;
    if (n < N) {
        const int rlen = deg[n];
        const int row = rowstart[n];
        const float ad = a_d[n];
        float4 acc = {0.f, 0.f, 0.f, 0.f};
        float den = 0.f;
        for (int base = 0; base < rlen; base += 64) {
            int m = rlen - base; if (m > 64) m = 64;
            int myS = 0; float ex = 0.f;
            if (j < m) {
                myS = srcs[row + base + j];
                float v = a_s[myS] + ad;
                v = v > 0.f ? v : NEG * v;
                ex = expf(v);
            }
            float ds = ex;
            #pragma unroll
            for (int off = 1; off < 64; off <<= 1) ds += __shfl_xor(ds, off);
            den += ds;
            int eb = 0;
            for (; eb + 16 <= m; eb += 16) {           // 4 gathers in flight
                int s4[4]; float e4[4]; float4 l4[4];
                #pragma unroll
                for (int ii = 0; ii < 4; ++ii) {
                    int e = eb + 4 * ii + q;
                    s4[ii] = __shfl(myS, e);
                    e4[ii] = __shfl(ex, e);
                }
                #pragma unroll
                for (int ii = 0; ii < 4; ++ii)
                    l4[ii] = *(const float4*)&h2[(size_t)s4[ii] * 64 + 4 * t];
                #pragma unroll
                for (int ii = 0; ii < 4; ++ii)
                    fma4(acc, e4[ii], l4[ii]);
            }
            for (; eb + 4 <= m; eb += 4) {
                int e = eb + q;
                int sk = __shfl(myS, e);
                float ek = __shfl(ex, e);
                float4 lk = *(const float4*)&h2[(size_t)sk * 64 + 4 * t];
                fma4(acc, ek, lk);
            }
            for (int k = eb; k < m; ++k) {
                int sk = __shfl(myS, k);
                float ek = __shfl(ex, k);
                if (q == (k & 3)) {
                    float4 lk = *(const float4*)&h2[(size_t)sk * 64 + 4 * t];
                    fma4(acc, ek, lk);
                }
            }
        }
        acc.x += __shfl_xor(acc.x, 16); acc.y += __shfl_xor(acc.y, 16);
        acc.z += __shfl_xor(acc.z, 16); acc.w += __shfl_xor(acc.w, 16);
        acc.x += __shfl_xor(acc.x, 32); acc.y += __shfl_xor(acc.y, 32);
        acc.z += __shfl_xor(acc.z, 32); acc.w += __shfl_xor(acc.w, 32);
        float4 b = *(const float4*)&b2[4 * t];
        float4 sc;
        sc.x = acc.x / den + b.x; sc.y = acc.y / den + b.y;
        sc.z = acc.z / den + b.z; sc.w = acc.w / den + b.w;
        float mv = sc.x; int mi = 4 * t;
        if (sc.y > mv) { mv = sc.y; mi = 4 * t + 1; }
        if (sc.z > mv) { mv = sc.z; mi = 4 * t + 2; }
        if (sc.w > mv) { mv = sc.w; mi = 4 * t + 3; }
        #pragma unroll
        for (int off = 1; off < 16; off <<= 1) {
            float ov = __shfl_xor(mv, off);
            int oi = __shfl_xor(mi, off);
            if (ov > mv || (ov == mv && oi < mi)) { mv = ov; mi = oi; }
        }
        float se = expf(sc.x - mv) + expf(sc.y - mv) + expf(sc.z - mv) + expf(sc.w - mv);
        #pragma unroll
        for (int off = 1; off < 16; off <<= 1) se += __shfl_xor(se, off);
        int lab = label[n];
        int comp = lab & 3;
        float cl = comp == 0 ? sc.x : comp == 1 ? sc.y : comp == 2 ? sc.z : sc.w;
        float sl = __shfl(cl, (j & 0x30) | (lab >> 2));
        if (j == 0) {
            snll[w] = mv + logf(se) - sl;
            dout[1 + n] = (float)mi;
            dout[1 + (size_t)N + n] = (float)lab;
        }
    }
    __syncthreads();
    if (tid == 0) {
        double bsum4 = (double)snll[0] + (double)snll[1]
                     + (double)snll[2] + (double)snll[3];
        atomicAdd(&bins[blockIdx.x & (NBINS - 1)], bsum4);
    }
}

// Single block of 256: reduce NBINS doubles -> loss
__global__ __launch_bounds__(256) void k_loss(
    const double* __restrict__ bins, float* __restrict__ dout, int N)
{
    __shared__ double sw[4];
    const int tid = threadIdx.x;
    double v = bins[tid];
    #pragma unroll
    for (int off = 1; off < 64; off <<= 1) v += __shfl_xor(v, off);
    if ((tid & 63) == 0) sw[tid >> 6] = v;
    __syncthreads();
    if (tid == 0)
        dout[0] = (float)((sw[0] + sw[1] + sw[2] + sw[3]) / (double)N);
}

extern "C" void kernel_launch(void* const* d_in, const int* in_sizes, int n_in,
                              void* d_out, int out_size, void* d_ws, size_t ws_size,
                              hipStream_t stream)
{
    const float* feat   = (const float*)d_in[1];
    const int*   edge   = (const int*)d_in[2];
    const int*   label  = (const int*)d_in[4];
    const float* W1     = (const float*)d_in[5];
    const float* att_s1 = (const float*)d_in[6];
    const float* att_d1 = (const float*)d_in[7];
    const float* b1     = (const float*)d_in[8];
    const float* W2     = (const float*)d_in[9];
    const float* att_s2 = (const float*)d_in[10];
    const float* att_d2 = (const float*)d_in[11];
    const float* b2     = (const float*)d_in[12];

    const int N = in_sizes[0];
    const int E = in_sizes[2] / 2;
    const int* src = edge;
    const int* dst = edge + E;

    // workspace layout:
    float* bufA = (float*)d_ws;               // N*64: h1 / h2 (no aliases)
    float* bufB = bufA + (size_t)N * 64;      // N*64: x; aliases CSR-build scratch
    float* a_s1 = bufB + (size_t)N * 64;      // N*8 (layer2: a_s2=[0..N), a_d2=[N..2N))
    float* a_d1 = a_s1 + (size_t)N * 8;       // N*8
    int*   deg  = (int*)(a_d1 + (size_t)N * 8); // N
    int*   rowstart = deg + N;                // N (absolute CSR row starts)
    int*   srcs = rowstart + N;               // E
    double* bins = (double*)(((uintptr_t)(srcs + E) + 7) & ~(uintptr_t)7);

    // Aliases in bufB — all dead before k_agg1 writes x:
    int* bucketed = (int*)bufB;               // E   packed (dst&127)<<17 | src
    int* btot  = bucketed + E;                // BINS*16 (padded: 1 counter / 64B line)
    int* gcur  = btot + BINS * 16;            // BINS*16 (padded cursors)
    int* bbase = gcur + BINS * 16;            // BINS
    int* bh    = bbase + BINS;                // GH*BINS per-block histograms

    float* a_s2 = a_s1;
    float* a_d2 = a_s1 + N;

    float* out = (float*)d_out;

    const int GH    = (E + CHUNK - 1) / CHUNK;
    const int G1    = (N + 63) / 64;
    const int NBUCK = (N + 127) / 128;

    hipMemsetAsync(btot, 0, (size_t)BINS * 16 * sizeof(int), stream);

    // bucket-hist (LDS atomics) overlapped with gemm1; then bucket scan; then
    // scatter into buckets; then per-bucket sort -> deg/rowstart/srcs.
    k_gemm1_hist<<<GH + G1, 256, 0, stream>>>(feat, W1, att_s1, att_d1,
                                              bufA, a_s1, a_d1,
                                              dst, btot, bh, N, E, GH);
    k_bscan  <<<1, 256, 0, stream>>>(btot, bbase, gcur, bins);
    k_scatter<<<GH, 256, 0, stream>>>(src, dst, bh, gcur, bucketed, E);
    k_seg    <<<NBUCK, 256, 0, stream>>>(btot, bbase, bucketed, deg, rowstart, srcs, N);

    k_agg1 <<<(N + 3) / 4, 256, 0, stream>>>(deg, rowstart, srcs, a_s1, a_d1,
                                             bufA, b1, bufB, N);
    k_gemm2<<<G1, 256, 0, stream>>>(bufB, W2, att_s2, att_d2, bufA, a_s2, a_d2, N);
    k_agg2 <<<(N + 3) / 4, 256, 0, stream>>>(deg, rowstart, srcs, a_s2, a_d2,
                                             bufA, b2, label, out, bins, N);
    k_loss <<<1, 256, 0, stream>>>(bins, out, N);
}

// Round 3
// 397.772 us; speedup vs baseline: 1.2909x; 1.0770x over previous
//
#include <hip/hip_runtime.h>
#include <cstdint>

#define NHEAD 8
#define D1 64      // H1*C1
#define IN_F 128
#define NEG 0.2f
#define NBINS 256  // loss partial-sum bins
#define BINS 1024  // dst buckets of 128 nodes each (bin = dst>>7); valid for N <= 131072
#define BSH 7
#define CHUNK 8192 // edges per hist/scatter block (32/thread)

__device__ __forceinline__ void fma4(float4& a, float s, const float4& v)
{
    a.x = fmaf(s, v.x, a.x); a.y = fmaf(s, v.y, a.y);
    a.z = fmaf(s, v.z, a.z); a.w = fmaf(s, v.w, a.w);
}

// ---------------- Fused: bucket-hist (first) & gemm1 ---------------------------
// Round-14: WRITE_SIZE stayed 89 MB with true-XCD partitioning -> device atomics
// resolve at the memory-side coherence point (~32B writeback each, ~16G/s wall).
// Fix: keep per-edge atomics in LDS. Per block: LDS hist over 8192 edges, then
// only ~782 global adds (no-return) into padded bucket totals.
__global__ __launch_bounds__(256) void k_gemm1_hist(
    const float* __restrict__ feat,
    const float* __restrict__ W1,
    const float* __restrict__ att_s,
    const float* __restrict__ att_d,
    float* __restrict__ h1, float* __restrict__ a_src, float* __restrict__ a_dst,
    const int* __restrict__ dst, int* __restrict__ btot, int* __restrict__ bh,
    int N, int E, int GH)
{
    __shared__ float Wh[32 * 64];   // gemm: [kk][c], 8 KB (hist reuses as int hist[1024])
    __shared__ float Fh[64 * 36];   // gemm: [r][kk], stride 36, 9.2 KB
    const int tid = threadIdx.x;

    if ((int)blockIdx.x < GH) {
        // -------- histogram branch: all per-edge atomics in LDS ---------------
        int* hist = (int*)Wh;
        for (int b = tid; b < BINS; b += 256) hist[b] = 0;
        __syncthreads();
        const int e0 = blockIdx.x * CHUNK;
        #pragma unroll
        for (int r = 0; r < 8; ++r) {
            int e = e0 + r * 1024 + tid * 4;
            if (e + 3 < E) {
                int4 d4 = *(const int4*)&dst[e];
                atomicAdd(&hist[d4.x >> BSH], 1);
                atomicAdd(&hist[d4.y >> BSH], 1);
                atomicAdd(&hist[d4.z >> BSH], 1);
                atomicAdd(&hist[d4.w >> BSH], 1);
            } else {
                for (int k = e; k < E && k < e + 4; ++k)
                    atomicAdd(&hist[dst[k] >> BSH], 1);
            }
        }
        __syncthreads();
        for (int b = tid; b < BINS; b += 256) {
            int c = hist[b];
            bh[(size_t)blockIdx.x * BINS + b] = c;      // coalesced 4 KB store
            if (c) atomicAdd(&btot[b * 16], c);         // no-return, padded line
        }
        return;
    }

    // -------- gemm1 branch: 64x64 tile, 4x4 register tile, K in 4 quarters ----
    const int tx = tid & 15, ty = tid >> 4;
    const int base = (blockIdx.x - GH) * 64;
    float4 acc0 = {0,0,0,0}, acc1 = {0,0,0,0}, acc2 = {0,0,0,0}, acc3 = {0,0,0,0};

    for (int p = 0; p < 4; ++p) {
        if (p) __syncthreads();
        for (int i = tid; i < 32 * 64; i += 256)
            Wh[i] = W1[p * 2048 + i];
        for (int i = tid; i < 64 * 32; i += 256) {
            int r = i >> 5, kk = i & 31;
            int n = base + r;
            Fh[r * 36 + kk] = (n < N) ? feat[(size_t)n * IN_F + p * 32 + kk] : 0.f;
        }
        __syncthreads();
        const float* wk = &Wh[4 * tx];
        const float* f0 = &Fh[(4 * ty + 0) * 36];
        const float* f1 = &Fh[(4 * ty + 1) * 36];
        const float* f2 = &Fh[(4 * ty + 2) * 36];
        const float* f3 = &Fh[(4 * ty + 3) * 36];
        #pragma unroll
        for (int kk = 0; kk < 32; kk += 4) {
            float4 fa = *(const float4*)&f0[kk];
            float4 fb = *(const float4*)&f1[kk];
            float4 fc = *(const float4*)&f2[kk];
            float4 fd = *(const float4*)&f3[kk];
            float4 w0 = *(const float4*)&wk[(kk + 0) * 64];
            float4 w1 = *(const float4*)&wk[(kk + 1) * 64];
            float4 w2 = *(const float4*)&wk[(kk + 2) * 64];
            float4 w3 = *(const float4*)&wk[(kk + 3) * 64];
            fma4(acc0, fa.x, w0); fma4(acc0, fa.y, w1); fma4(acc0, fa.z, w2); fma4(acc0, fa.w, w3);
            fma4(acc1, fb.x, w0); fma4(acc1, fb.y, w1); fma4(acc1, fb.z, w2); fma4(acc1, fb.w, w3);
            fma4(acc2, fc.x, w0); fma4(acc2, fc.y, w1); fma4(acc2, fc.z, w2); fma4(acc2, fc.w, w3);
            fma4(acc3, fd.x, w0); fma4(acc3, fd.y, w1); fma4(acc3, fd.z, w2); fma4(acc3, fd.w, w3);
        }
    }
    const float4 as4 = *(const float4*)&att_s[4 * tx];
    const float4 ad4 = *(const float4*)&att_d[4 * tx];
    float4 accs[4] = {acc0, acc1, acc2, acc3};
    #pragma unroll
    for (int i = 0; i < 4; ++i) {
        int n = base + 4 * ty + i;
        if (n < N) {
            *(float4*)&h1[(size_t)n * D1 + 4 * tx] = accs[i];
            float ps = accs[i].x * as4.x + accs[i].y * as4.y + accs[i].z * as4.z + accs[i].w * as4.w;
            float pd = accs[i].x * ad4.x + accs[i].y * ad4.y + accs[i].z * ad4.z + accs[i].w * ad4.w;
            ps += __shfl_xor(ps, 1);
            pd += __shfl_xor(pd, 1);
            if ((tx & 1) == 0) {
                a_src[n * NHEAD + (tx >> 1)] = ps;
                a_dst[n * NHEAD + (tx >> 1)] = pd;
            }
        }
    }
}

__device__ __forceinline__ int block_incl_scan(int v, int tid, int* lds4)
{
    int lane = tid & 63, w = tid >> 6;
    #pragma unroll
    for (int off = 1; off < 64; off <<= 1) {
        int t = __shfl_up(v, off);
        if (lane >= off) v += t;
    }
    if (lane == 63) lds4[w] = v;
    __syncthreads();
    int add = 0;
    #pragma unroll
    for (int i = 0; i < 4; ++i)
        if (i < w) add += lds4[i];
    __syncthreads();
    return v + add;
}

// Scan the 1024 bucket totals -> bucket bases; init the padded global cursors;
// zero the loss bins (folded here).
__global__ __launch_bounds__(256) void k_bscan(
    const int* __restrict__ btot, int* __restrict__ bbase, int* __restrict__ gcur,
    double* __restrict__ bins)
{
    __shared__ int lds4[4];
    const int tid = threadIdx.x;
    bins[tid] = 0.0;
    int c0 = btot[(4 * tid + 0) * 16];
    int c1 = btot[(4 * tid + 1) * 16];
    int c2 = btot[(4 * tid + 2) * 16];
    int c3 = btot[(4 * tid + 3) * 16];
    int v = c0 + c1 + c2 + c3;
    int incl = block_incl_scan(v, tid, lds4);
    int b0 = incl - v, b1 = b0 + c0, b2 = b1 + c1, b3 = b2 + c2;
    bbase[4 * tid + 0] = b0; gcur[(4 * tid + 0) * 16] = b0;
    bbase[4 * tid + 1] = b1; gcur[(4 * tid + 1) * 16] = b1;
    bbase[4 * tid + 2] = b2; gcur[(4 * tid + 2) * 16] = b2;
    bbase[4 * tid + 3] = b3; gcur[(4 * tid + 3) * 16] = b3;
}

// Scatter edges into their dst-bucket. Per block: ~782 with-return global adds
// (one per non-empty bucket, padded cursor lines) to reserve space; per-edge
// ranks come from LDS cursors. Packed entry: (dst&127)<<17 | src  (N < 2^17).
__global__ __launch_bounds__(256) void k_scatter(
    const int* __restrict__ src, const int* __restrict__ dst,
    const int* __restrict__ bh, int* __restrict__ gcur,
    int* __restrict__ bucketed, int E)
{
    __shared__ int base[BINS], cur[BINS];
    const int tid = threadIdx.x;
    for (int b = tid; b < BINS; b += 256) {
        cur[b] = 0;
        int c = bh[(size_t)blockIdx.x * BINS + b];
        if (c) base[b] = atomicAdd(&gcur[b * 16], c);
    }
    __syncthreads();
    const int e0 = blockIdx.x * CHUNK;
    #pragma unroll
    for (int r = 0; r < 8; ++r) {
        int e = e0 + r * 1024 + tid * 4;
        if (e + 3 < E) {
            int4 d4 = *(const int4*)&dst[e];
            int4 s4 = *(const int4*)&src[e];
            int bx, rx;
            bx = d4.x >> BSH; rx = atomicAdd(&cur[bx], 1); bucketed[base[bx] + rx] = ((d4.x & 127) << 17) | s4.x;
            bx = d4.y >> BSH; rx = atomicAdd(&cur[bx], 1); bucketed[base[bx] + rx] = ((d4.y & 127) << 17) | s4.y;
            bx = d4.z >> BSH; rx = atomicAdd(&cur[bx], 1); bucketed[base[bx] + rx] = ((d4.z & 127) << 17) | s4.z;
            bx = d4.w >> BSH; rx = atomicAdd(&cur[bx], 1); bucketed[base[bx] + rx] = ((d4.w & 127) << 17) | s4.w;
        } else {
            for (int k = e; k < E && k < e + 4; ++k) {
                int d = dst[k];
                int bx = d >> BSH;
                int rx = atomicAdd(&cur[bx], 1);
                bucketed[base[bx] + rx] = ((d & 127) << 17) | src[k];
            }
        }
    }
}

// One block per bucket: count 128 local nodes in LDS, scan in LDS, emit
// deg/rowstart directly (rowstart = bucket_base + local_base -> no global scan),
// then scatter the bucket into final CSR positions (contiguous ~9 KB region).
__global__ __launch_bounds__(256) void k_seg(
    const int* __restrict__ btot, const int* __restrict__ bbase,
    const int* __restrict__ bucketed,
    int* __restrict__ deg, int* __restrict__ rowstart, int* __restrict__ srcs, int N)
{
    __shared__ int cnt[128], cur[128], lb[128];
    const int tid = threadIdx.x;
    const int b = blockIdx.x;
    const int gs = bbase[b];
    const int sz = btot[b * 16];
    if (tid < 128) { cnt[tid] = 0; cur[tid] = 0; }
    __syncthreads();
    for (int i = tid; i < sz; i += 256)
        atomicAdd(&cnt[bucketed[gs + i] >> 17], 1);
    __syncthreads();
    if (tid < 128) lb[tid] = cnt[tid];
    __syncthreads();
    #pragma unroll
    for (int off = 1; off < 128; off <<= 1) {
        int t = 0;
        if (tid < 128 && tid >= off) t = lb[tid - off];
        __syncthreads();
        if (tid < 128 && tid >= off) lb[tid] += t;
        __syncthreads();
    }
    if (tid < 128) {
        int ex = lb[tid] - cnt[tid];   // exclusive local base
        lb[tid] = ex;
        int d = b * 128 + tid;
        if (d < N) { deg[d] = cnt[tid]; rowstart[d] = gs + ex; }
    }
    __syncthreads();
    for (int i = tid; i < sz; i += 256) {
        int v = bucketed[gs + i];
        int d7 = v >> 17;
        int r = atomicAdd(&cur[d7], 1);
        srcs[gs + lb[d7] + r] = v & 0x1FFFF;
    }
}

// ---------------- Layer-1 aggregation ------------------------------------------
// Round-15: phase A (denom/weights, lane=(slot c, head hh)) kept verbatim;
// gather phase rewritten to float4: lane (q=j>>4, t=j&15) handles edges
// {2q,2q+1}, feature quad t, weight from head t>>1 via shfl. 48 -> 18 insts
// per 8 edges; same 8 rows in flight.
__global__ __launch_bounds__(256) void k_agg1(
    const int* __restrict__ deg, const int* __restrict__ rowstart,
    const int* __restrict__ srcs,
    const float* __restrict__ a_s, const float* __restrict__ a_d,
    const float* __restrict__ h1, const float* __restrict__ b1,
    float* __restrict__ x, int N)
{
    const int tid = threadIdx.x, w = tid >> 6, j = tid & 63;
    const int c = j & 7, hh = j >> 3;      // phase A: edge-slot c, head hh
    const int t = j & 15, q = j >> 4;      // phase B: feature-quad t, edge-pair q
    const int n = blockIdx.x * 4 + w;
    if (n >= N) return;
    const int rlen = deg[n];
    const int row = rowstart[n];
    const float ad = a_d[n * NHEAD + hh];
    float4 acc = {0.f, 0.f, 0.f, 0.f};
    float den = 0.f;
    int m = rlen < 8 ? rlen : 8;
    int myS   = (c < m) ? srcs[row + c] : 0;
    float av  = (c < m) ? a_s[myS * NHEAD + hh] : 0.f;
    for (int base = 0; base < rlen; base += 8) {
        int mn = rlen - base - 8; if (mn > 8) mn = 8; if (mn < 0) mn = 0;
        int   myS_n = (c < mn) ? srcs[row + base + 8 + c] : 0;
        float av_n  = (c < mn) ? a_s[myS_n * NHEAD + hh] : 0.f;
        float ex = 0.f;
        if (c < m) {
            float v = av + ad;
            v = v > 0.f ? v : NEG * v;
            ex = expf(v);
        }
        float ds = ex;                      // per-head denom: aligned 8-lane group reduce
        ds += __shfl_xor(ds, 1);
        ds += __shfl_xor(ds, 2);
        ds += __shfl_xor(ds, 4);
        den += ds;
        // phase B: edges k = 2q, 2q+1 (ex=0 for k>=m -> safe, row 0 read)
        int   s0 = __shfl(myS, 2 * q);
        int   s1 = __shfl(myS, 2 * q + 1);
        float e0 = __shfl(ex, ((t >> 1) << 3) | (2 * q));
        float e1 = __shfl(ex, ((t >> 1) << 3) | (2 * q + 1));
        float4 l0 = *(const float4*)&h1[(size_t)s0 * D1 + 4 * t];
        float4 l1 = *(const float4*)&h1[(size_t)s1 * D1 + 4 * t];
        fma4(acc, e0, l0);
        fma4(acc, e1, l1);
        myS = myS_n; av = av_n; m = mn;
    }
    // merge the 4 q-replicas
    acc.x += __shfl_xor(acc.x, 16); acc.y += __shfl_xor(acc.y, 16);
    acc.z += __shfl_xor(acc.z, 16); acc.w += __shfl_xor(acc.w, 16);
    acc.x += __shfl_xor(acc.x, 32); acc.y += __shfl_xor(acc.y, 32);
    acc.z += __shfl_xor(acc.z, 32); acc.w += __shfl_xor(acc.w, 32);
    float dd = __shfl(den, (t >> 1) << 3);   // den for head t>>1 (lane c=0,hh=t>>1)
    if (q == 0) {
        float4 b = *(const float4*)&b1[4 * t];
        float4 o;
        o.x = acc.x / dd + b.x; o.y = acc.y / dd + b.y;
        o.z = acc.z / dd + b.z; o.w = acc.w / dd + b.w;
        o.x = o.x > 0.f ? o.x : expm1f(o.x);
        o.y = o.y > 0.f ? o.y : expm1f(o.y);
        o.z = o.z > 0.f ? o.z : expm1f(o.z);
        o.w = o.w > 0.f ? o.w : expm1f(o.w);
        *(float4*)&x[(size_t)n * D1 + 4 * t] = o;
    }
}

// ---------------- Kernel D: h2 = x @ W2, a_src2/a_dst2 (4x4 register tile) ----------------
__global__ __launch_bounds__(256) void k_gemm2(
    const float* __restrict__ x,
    const float* __restrict__ W2,
    const float* __restrict__ att_s,
    const float* __restrict__ att_d,
    float* __restrict__ h2, float* __restrict__ a_src, float* __restrict__ a_dst,
    int N)
{
    __shared__ float Wh[64 * 64];
    __shared__ float Fh[64 * 68];
    const int tid = threadIdx.x;
    const int tx = tid & 15, ty = tid >> 4;
    const int base = blockIdx.x * 64;
    for (int i = tid; i < 64 * 64; i += 256)
        Wh[i] = W2[i];
    for (int i = tid; i < 64 * 64; i += 256) {
        int r = i >> 6, kk = i & 63;
        int n = base + r;
        Fh[r * 68 + kk] = (n < N) ? x[(size_t)n * 64 + kk] : 0.f;
    }
    __syncthreads();
    float4 acc0 = {0,0,0,0}, acc1 = {0,0,0,0}, acc2 = {0,0,0,0}, acc3 = {0,0,0,0};
    const float* wk = &Wh[4 * tx];
    const float* f0 = &Fh[(4 * ty + 0) * 68];
    const float* f1 = &Fh[(4 * ty + 1) * 68];
    const float* f2 = &Fh[(4 * ty + 2) * 68];
    const float* f3 = &Fh[(4 * ty + 3) * 68];
    #pragma unroll 4
    for (int kk = 0; kk < 64; kk += 4) {
        float4 fa = *(const float4*)&f0[kk];
        float4 fb = *(const float4*)&f1[kk];
        float4 fc = *(const float4*)&f2[kk];
        float4 fd = *(const float4*)&f3[kk];
        float4 w0 = *(const float4*)&wk[(kk + 0) * 64];
        float4 w1 = *(const float4*)&wk[(kk + 1) * 64];
        float4 w2 = *(const float4*)&wk[(kk + 2) * 64];
        float4 w3 = *(const float4*)&wk[(kk + 3) * 64];
        fma4(acc0, fa.x, w0); fma4(acc0, fa.y, w1); fma4(acc0, fa.z, w2); fma4(acc0, fa.w, w3);
        fma4(acc1, fb.x, w0); fma4(acc1, fb.y, w1); fma4(acc1, fb.z, w2); fma4(acc1, fb.w, w3);
        fma4(acc2, fc.x, w0); fma4(acc2, fc.y, w1); fma4(acc2, fc.z, w2); fma4(acc2, fc.w, w3);
        fma4(acc3, fd.x, w0); fma4(acc3, fd.y, w1); fma4(acc3, fd.z, w2); fma4(acc3, fd.w, w3);
    }
    const float4 as4 = *(const float4*)&att_s[4 * tx];
    const float4 ad4 = *(const float4*)&att_d[4 * tx];
    float4 accs[4] = {acc0, acc1, acc2, acc3};
    #pragma unroll
    for (int i = 0; i < 4; ++i) {
        int n = base + 4 * ty + i;
        if (n < N) {
            *(float4*)&h2[(size_t)n * 64 + 4 * tx] = accs[i];
            float ps = accs[i].x * as4.x + accs[i].y * as4.y + accs[i].z * as4.z + accs[i].w * as4.w;
            float pd = accs[i].x * ad4.x + accs[i].y * ad4.y + accs[i].z * ad4.z + accs[i].w * ad4.w;
            ps += __shfl_xor(ps, 1); pd += __shfl_xor(pd, 1);
            ps += __shfl_xor(ps, 2); pd += __shfl_xor(pd, 2);
            ps += __shfl_xor(ps, 4); pd += __shfl_xor(pd, 4);
            ps += __shfl_xor(ps, 8); pd += __shfl_xor(pd, 8);
            if (tx == 0) { a_src[n] = ps; a_dst[n] = pd; }
        }
    }
}

// ---------------- Layer-2 aggregation + bias + log-softmax + argmax + NLL ------
// Round-15: 4 nodes per wave (16 lanes each) -> per-node epilogue cost /4,
// denom phase ~fully occupied at deg~17, 16 float4 gathers in flight per wave.
// Per-edge (src, ex) staged in LDS (int2), read back as 16-lane broadcast.
__global__ __launch_bounds__(256) void k_agg2(
    const int* __restrict__ deg, const int* __restrict__ rowstart,
    const int* __restrict__ srcs,
    const float* __restrict__ a_s, const float* __restrict__ a_d,
    const float* __restrict__ h2, const float* __restrict__ b2,
    const int* __restrict__ label,
    float* __restrict__ dout, double* __restrict__ bins, int N)
{
    __shared__ int2 sx[4][64];
    __shared__ float snll[16];
    const int tid = threadIdx.x, w = tid >> 6, j = tid & 63;
    const int t = j & 15, g16 = j & 0x30;  // node's 16-lane group base within wave
    const int n = blockIdx.x * 16 + (tid >> 4);
    if (tid < 16) snll[tid] = 0.f;
    __syncthreads();
    const bool valid = (n < N);
    const int rlen = valid ? deg[n] : 0;
    const int row  = valid ? rowstart[n] : 0;
    const float ad = valid ? a_d[n] : 0.f;
    float4 acc = {0.f, 0.f, 0.f, 0.f};
    float den = 0.f;
    for (int base = 0; base < rlen; base += 16) {
        int m = rlen - base; if (m > 16) m = 16;
        int myS = 0; float ex = 0.f;
        if (t < m) {
            myS = srcs[row + base + t];
            float v = a_s[myS] + ad;
            v = v > 0.f ? v : NEG * v;
            ex = expf(v);
        }
        float ds = ex;
        ds += __shfl_xor(ds, 1); ds += __shfl_xor(ds, 2);
        ds += __shfl_xor(ds, 4); ds += __shfl_xor(ds, 8);
        den += ds;
        sx[w][j] = make_int2(myS, __float_as_int(ex));
        asm volatile("s_waitcnt lgkmcnt(0)" ::: "memory");
        for (int kb = 0; kb < m; kb += 4) {            // kb in {0,4,8,12}: idx <= 15
            int2 p0 = sx[w][g16 | (kb + 0)];
            int2 p1 = sx[w][g16 | (kb + 1)];
            int2 p2 = sx[w][g16 | (kb + 2)];
            int2 p3 = sx[w][g16 | (kb + 3)];
            float4 l0 = *(const float4*)&h2[(size_t)p0.x * 64 + 4 * t];
            float4 l1 = *(const float4*)&h2[(size_t)p1.x * 64 + 4 * t];
            float4 l2 = *(const float4*)&h2[(size_t)p2.x * 64 + 4 * t];
            float4 l3 = *(const float4*)&h2[(size_t)p3.x * 64 + 4 * t];
            fma4(acc, __int_as_float(p0.y), l0);
            fma4(acc, __int_as_float(p1.y), l1);
            fma4(acc, __int_as_float(p2.y), l2);
            fma4(acc, __int_as_float(p3.y), l3);
        }
        asm volatile("s_waitcnt lgkmcnt(0)" ::: "memory");  // reads drain before rewrite
    }
    float4 b = *(const float4*)&b2[4 * t];
    float4 sc;
    sc.x = acc.x / den + b.x; sc.y = acc.y / den + b.y;
    sc.z = acc.z / den + b.z; sc.w = acc.w / den + b.w;
    float mv = sc.x; int mi = 4 * t;
    if (sc.y > mv) { mv = sc.y; mi = 4 * t + 1; }
    if (sc.z > mv) { mv = sc.z; mi = 4 * t + 2; }
    if (sc.w > mv) { mv = sc.w; mi = 4 * t + 3; }
    #pragma unroll
    for (int off = 1; off < 16; off <<= 1) {
        float ov = __shfl_xor(mv, off);
        int oi = __shfl_xor(mi, off);
        if (ov > mv || (ov == mv && oi < mi)) { mv = ov; mi = oi; }
    }
    float se = expf(sc.x - mv) + expf(sc.y - mv) + expf(sc.z - mv) + expf(sc.w - mv);
    #pragma unroll
    for (int off = 1; off < 16; off <<= 1) se += __shfl_xor(se, off);
    int lab = valid ? label[n] : 0;
    int comp = lab & 3;
    float cl = comp == 0 ? sc.x : comp == 1 ? sc.y : comp == 2 ? sc.z : sc.w;
    float sl = __shfl(cl, g16 | (lab >> 2));
    if (t == 0 && valid) {
        snll[tid >> 4] = mv + logf(se) - sl;
        dout[1 + n] = (float)mi;
        dout[1 + (size_t)N + n] = (float)lab;
    }
    __syncthreads();
    if (tid == 0) {
        double bs = 0.0;
        #pragma unroll
        for (int i = 0; i < 16; ++i) bs += (double)snll[i];
        atomicAdd(&bins[blockIdx.x & (NBINS - 1)], bs);
    }
}

// Single block of 256: reduce NBINS doubles -> loss
__global__ __launch_bounds__(256) void k_loss(
    const double* __restrict__ bins, float* __restrict__ dout, int N)
{
    __shared__ double sw[4];
    const int tid = threadIdx.x;
    double v = bins[tid];
    #pragma unroll
    for (int off = 1; off < 64; off <<= 1) v += __shfl_xor(v, off);
    if ((tid & 63) == 0) sw[tid >> 6] = v;
    __syncthreads();
    if (tid == 0)
        dout[0] = (float)((sw[0] + sw[1] + sw[2] + sw[3]) / (double)N);
}

extern "C" void kernel_launch(void* const* d_in, const int* in_sizes, int n_in,
                              void* d_out, int out_size, void* d_ws, size_t ws_size,
                              hipStream_t stream)
{
    const float* feat   = (const float*)d_in[1];
    const int*   edge   = (const int*)d_in[2];
    const int*   label  = (const int*)d_in[4];
    const float* W1     = (const float*)d_in[5];
    const float* att_s1 = (const float*)d_in[6];
    const float* att_d1 = (const float*)d_in[7];
    const float* b1     = (const float*)d_in[8];
    const float* W2     = (const float*)d_in[9];
    const float* att_s2 = (const float*)d_in[10];
    const float* att_d2 = (const float*)d_in[11];
    const float* b2     = (const float*)d_in[12];

    const int N = in_sizes[0];
    const int E = in_sizes[2] / 2;
    const int* src = edge;
    const int* dst = edge + E;

    // workspace layout:
    float* bufA = (float*)d_ws;               // N*64: h1 / h2 (no aliases)
    float* bufB = bufA + (size_t)N * 64;      // N*64: x; aliases CSR-build scratch
    float* a_s1 = bufB + (size_t)N * 64;      // N*8 (layer2: a_s2=[0..N), a_d2=[N..2N))
    float* a_d1 = a_s1 + (size_t)N * 8;       // N*8
    int*   deg  = (int*)(a_d1 + (size_t)N * 8); // N
    int*   rowstart = deg + N;                // N (absolute CSR row starts)
    int*   srcs = rowstart + N;               // E
    double* bins = (double*)(((uintptr_t)(srcs + E) + 7) & ~(uintptr_t)7);

    // Aliases in bufB — all dead before k_agg1 writes x:
    int* bucketed = (int*)bufB;               // E   packed (dst&127)<<17 | src
    int* btot  = bucketed + E;                // BINS*16 (padded: 1 counter / 64B line)
    int* gcur  = btot + BINS * 16;            // BINS*16 (padded cursors)
    int* bbase = gcur + BINS * 16;            // BINS
    int* bh    = bbase + BINS;                // GH*BINS per-block histograms

    float* a_s2 = a_s1;
    float* a_d2 = a_s1 + N;

    float* out = (float*)d_out;

    const int GH    = (E + CHUNK - 1) / CHUNK;
    const int G1    = (N + 63) / 64;
    const int NBUCK = (N + 127) / 128;

    hipMemsetAsync(btot, 0, (size_t)BINS * 16 * sizeof(int), stream);

    // bucket-hist (LDS atomics) overlapped with gemm1; then bucket scan; then
    // scatter into buckets; then per-bucket sort -> deg/rowstart/srcs.
    k_gemm1_hist<<<GH + G1, 256, 0, stream>>>(feat, W1, att_s1, att_d1,
                                              bufA, a_s1, a_d1,
                                              dst, btot, bh, N, E, GH);
    k_bscan  <<<1, 256, 0, stream>>>(btot, bbase, gcur, bins);
    k_scatter<<<GH, 256, 0, stream>>>(src, dst, bh, gcur, bucketed, E);
    k_seg    <<<NBUCK, 256, 0, stream>>>(btot, bbase, bucketed, deg, rowstart, srcs, N);

    k_agg1 <<<(N + 3) / 4, 256, 0, stream>>>(deg, rowstart, srcs, a_s1, a_d1,
                                             bufA, b1, bufB, N);
    k_gemm2<<<G1, 256, 0, stream>>>(bufB, W2, att_s2, att_d2, bufA, a_s2, a_d2, N);
    k_agg2 <<<(N + 15) / 16, 256, 0, stream>>>(deg, rowstart, srcs, a_s2, a_d2,
                                               bufA, b2, label, out, bins, N);
    k_loss <<<1, 256, 0, stream>>>(bins, out, N);
}

// Round 4
// 390.276 us; speedup vs baseline: 1.3157x; 1.0192x over previous
//
#include <hip/hip_runtime.h>
#include <cstdint>

#define NHEAD 8
#define D1 64      // H1*C1
#define IN_F 128
#define NEG 0.2f
#define NBINS 256  // loss partial-sum bins
#define BINS 1024  // dst buckets of 128 nodes each (bin = dst>>7); valid for N <= 131072
#define BSH 7
#define CHUNK 8192 // edges per hist/scatter block (32/thread)

__device__ __forceinline__ void fma4(float4& a, float s, const float4& v)
{
    a.x = fmaf(s, v.x, a.x); a.y = fmaf(s, v.y, a.y);
    a.z = fmaf(s, v.z, a.z); a.w = fmaf(s, v.w, a.w);
}

// ---------------- Fused: bucket-hist (first) & gemm1 ---------------------------
// Round-14: WRITE_SIZE stayed 89 MB with true-XCD partitioning -> device atomics
// resolve at the memory-side coherence point (~32B writeback each, ~16G/s wall).
// Fix: keep per-edge atomics in LDS. Per block: LDS hist over 8192 edges, then
// only ~782 global adds (no-return) into padded bucket totals.
__global__ __launch_bounds__(256) void k_gemm1_hist(
    const float* __restrict__ feat,
    const float* __restrict__ W1,
    const float* __restrict__ att_s,
    const float* __restrict__ att_d,
    float* __restrict__ h1, float* __restrict__ a_src, float* __restrict__ a_dst,
    const int* __restrict__ dst, int* __restrict__ btot, int* __restrict__ bh,
    int N, int E, int GH)
{
    __shared__ float Wh[32 * 64];   // gemm: [kk][c], 8 KB (hist reuses as int hist[1024])
    __shared__ float Fh[64 * 36];   // gemm: [r][kk], stride 36, 9.2 KB
    const int tid = threadIdx.x;

    if ((int)blockIdx.x < GH) {
        // -------- histogram branch: all per-edge atomics in LDS ---------------
        int* hist = (int*)Wh;
        for (int b = tid; b < BINS; b += 256) hist[b] = 0;
        __syncthreads();
        const int e0 = blockIdx.x * CHUNK;
        #pragma unroll
        for (int r = 0; r < 8; ++r) {
            int e = e0 + r * 1024 + tid * 4;
            if (e + 3 < E) {
                int4 d4 = *(const int4*)&dst[e];
                atomicAdd(&hist[d4.x >> BSH], 1);
                atomicAdd(&hist[d4.y >> BSH], 1);
                atomicAdd(&hist[d4.z >> BSH], 1);
                atomicAdd(&hist[d4.w >> BSH], 1);
            } else {
                for (int k = e; k < E && k < e + 4; ++k)
                    atomicAdd(&hist[dst[k] >> BSH], 1);
            }
        }
        __syncthreads();
        for (int b = tid; b < BINS; b += 256) {
            int c = hist[b];
            bh[(size_t)blockIdx.x * BINS + b] = c;      // coalesced 4 KB store
            if (c) atomicAdd(&btot[b * 16], c);         // no-return, padded line
        }
        return;
    }

    // -------- gemm1 branch: 64x64 tile, 4x4 register tile, K in 4 quarters ----
    const int tx = tid & 15, ty = tid >> 4;
    const int base = (blockIdx.x - GH) * 64;
    float4 acc0 = {0,0,0,0}, acc1 = {0,0,0,0}, acc2 = {0,0,0,0}, acc3 = {0,0,0,0};

    for (int p = 0; p < 4; ++p) {
        if (p) __syncthreads();
        for (int i = tid; i < 32 * 64; i += 256)
            Wh[i] = W1[p * 2048 + i];
        for (int i = tid; i < 64 * 32; i += 256) {
            int r = i >> 5, kk = i & 31;
            int n = base + r;
            Fh[r * 36 + kk] = (n < N) ? feat[(size_t)n * IN_F + p * 32 + kk] : 0.f;
        }
        __syncthreads();
        const float* wk = &Wh[4 * tx];
        const float* f0 = &Fh[(4 * ty + 0) * 36];
        const float* f1 = &Fh[(4 * ty + 1) * 36];
        const float* f2 = &Fh[(4 * ty + 2) * 36];
        const float* f3 = &Fh[(4 * ty + 3) * 36];
        #pragma unroll
        for (int kk = 0; kk < 32; kk += 4) {
            float4 fa = *(const float4*)&f0[kk];
            float4 fb = *(const float4*)&f1[kk];
            float4 fc = *(const float4*)&f2[kk];
            float4 fd = *(const float4*)&f3[kk];
            float4 w0 = *(const float4*)&wk[(kk + 0) * 64];
            float4 w1 = *(const float4*)&wk[(kk + 1) * 64];
            float4 w2 = *(const float4*)&wk[(kk + 2) * 64];
            float4 w3 = *(const float4*)&wk[(kk + 3) * 64];
            fma4(acc0, fa.x, w0); fma4(acc0, fa.y, w1); fma4(acc0, fa.z, w2); fma4(acc0, fa.w, w3);
            fma4(acc1, fb.x, w0); fma4(acc1, fb.y, w1); fma4(acc1, fb.z, w2); fma4(acc1, fb.w, w3);
            fma4(acc2, fc.x, w0); fma4(acc2, fc.y, w1); fma4(acc2, fc.z, w2); fma4(acc2, fc.w, w3);
            fma4(acc3, fd.x, w0); fma4(acc3, fd.y, w1); fma4(acc3, fd.z, w2); fma4(acc3, fd.w, w3);
        }
    }
    const float4 as4 = *(const float4*)&att_s[4 * tx];
    const float4 ad4 = *(const float4*)&att_d[4 * tx];
    float4 accs[4] = {acc0, acc1, acc2, acc3};
    #pragma unroll
    for (int i = 0; i < 4; ++i) {
        int n = base + 4 * ty + i;
        if (n < N) {
            *(float4*)&h1[(size_t)n * D1 + 4 * tx] = accs[i];
            float ps = accs[i].x * as4.x + accs[i].y * as4.y + accs[i].z * as4.z + accs[i].w * as4.w;
            float pd = accs[i].x * ad4.x + accs[i].y * ad4.y + accs[i].z * ad4.z + accs[i].w * ad4.w;
            ps += __shfl_xor(ps, 1);
            pd += __shfl_xor(pd, 1);
            if ((tx & 1) == 0) {
                a_src[n * NHEAD + (tx >> 1)] = ps;
                a_dst[n * NHEAD + (tx >> 1)] = pd;
            }
        }
    }
}

__device__ __forceinline__ int block_incl_scan(int v, int tid, int* lds4)
{
    int lane = tid & 63, w = tid >> 6;
    #pragma unroll
    for (int off = 1; off < 64; off <<= 1) {
        int t = __shfl_up(v, off);
        if (lane >= off) v += t;
    }
    if (lane == 63) lds4[w] = v;
    __syncthreads();
    int add = 0;
    #pragma unroll
    for (int i = 0; i < 4; ++i)
        if (i < w) add += lds4[i];
    __syncthreads();
    return v + add;
}

// Scan the 1024 bucket totals -> bucket bases; init the padded global cursors;
// zero the loss bins (folded here).
__global__ __launch_bounds__(256) void k_bscan(
    const int* __restrict__ btot, int* __restrict__ bbase, int* __restrict__ gcur,
    double* __restrict__ bins)
{
    __shared__ int lds4[4];
    const int tid = threadIdx.x;
    bins[tid] = 0.0;
    int c0 = btot[(4 * tid + 0) * 16];
    int c1 = btot[(4 * tid + 1) * 16];
    int c2 = btot[(4 * tid + 2) * 16];
    int c3 = btot[(4 * tid + 3) * 16];
    int v = c0 + c1 + c2 + c3;
    int incl = block_incl_scan(v, tid, lds4);
    int b0 = incl - v, b1 = b0 + c0, b2 = b1 + c1, b3 = b2 + c2;
    bbase[4 * tid + 0] = b0; gcur[(4 * tid + 0) * 16] = b0;
    bbase[4 * tid + 1] = b1; gcur[(4 * tid + 1) * 16] = b1;
    bbase[4 * tid + 2] = b2; gcur[(4 * tid + 2) * 16] = b2;
    bbase[4 * tid + 3] = b3; gcur[(4 * tid + 3) * 16] = b3;
}

// Scatter edges into their dst-bucket. Per block: ~782 with-return global adds
// (one per non-empty bucket, padded cursor lines) to reserve space; per-edge
// ranks come from LDS cursors. Packed entry: (dst&127)<<17 | src  (N < 2^17).
__global__ __launch_bounds__(256) void k_scatter(
    const int* __restrict__ src, const int* __restrict__ dst,
    const int* __restrict__ bh, int* __restrict__ gcur,
    int* __restrict__ bucketed, int E)
{
    __shared__ int base[BINS], cur[BINS];
    const int tid = threadIdx.x;
    for (int b = tid; b < BINS; b += 256) {
        cur[b] = 0;
        int c = bh[(size_t)blockIdx.x * BINS + b];
        if (c) base[b] = atomicAdd(&gcur[b * 16], c);
    }
    __syncthreads();
    const int e0 = blockIdx.x * CHUNK;
    #pragma unroll
    for (int r = 0; r < 8; ++r) {
        int e = e0 + r * 1024 + tid * 4;
        if (e + 3 < E) {
            int4 d4 = *(const int4*)&dst[e];
            int4 s4 = *(const int4*)&src[e];
            int bx, rx;
            bx = d4.x >> BSH; rx = atomicAdd(&cur[bx], 1); bucketed[base[bx] + rx] = ((d4.x & 127) << 17) | s4.x;
            bx = d4.y >> BSH; rx = atomicAdd(&cur[bx], 1); bucketed[base[bx] + rx] = ((d4.y & 127) << 17) | s4.y;
            bx = d4.z >> BSH; rx = atomicAdd(&cur[bx], 1); bucketed[base[bx] + rx] = ((d4.z & 127) << 17) | s4.z;
            bx = d4.w >> BSH; rx = atomicAdd(&cur[bx], 1); bucketed[base[bx] + rx] = ((d4.w & 127) << 17) | s4.w;
        } else {
            for (int k = e; k < E && k < e + 4; ++k) {
                int d = dst[k];
                int bx = d >> BSH;
                int rx = atomicAdd(&cur[bx], 1);
                bucketed[base[bx] + rx] = ((d & 127) << 17) | src[k];
            }
        }
    }
}

// One block per bucket: count 128 local nodes in LDS, scan in LDS, emit
// deg/rowstart directly (rowstart = bucket_base + local_base -> no global scan),
// then scatter the bucket into final CSR positions (contiguous ~9 KB region).
__global__ __launch_bounds__(256) void k_seg(
    const int* __restrict__ btot, const int* __restrict__ bbase,
    const int* __restrict__ bucketed,
    int* __restrict__ deg, int* __restrict__ rowstart, int* __restrict__ srcs, int N)
{
    __shared__ int cnt[128], cur[128], lb[128];
    const int tid = threadIdx.x;
    const int b = blockIdx.x;
    const int gs = bbase[b];
    const int sz = btot[b * 16];
    if (tid < 128) { cnt[tid] = 0; cur[tid] = 0; }
    __syncthreads();
    for (int i = tid; i < sz; i += 256)
        atomicAdd(&cnt[bucketed[gs + i] >> 17], 1);
    __syncthreads();
    if (tid < 128) lb[tid] = cnt[tid];
    __syncthreads();
    #pragma unroll
    for (int off = 1; off < 128; off <<= 1) {
        int t = 0;
        if (tid < 128 && tid >= off) t = lb[tid - off];
        __syncthreads();
        if (tid < 128 && tid >= off) lb[tid] += t;
        __syncthreads();
    }
    if (tid < 128) {
        int ex = lb[tid] - cnt[tid];   // exclusive local base
        lb[tid] = ex;
        int d = b * 128 + tid;
        if (d < N) { deg[d] = cnt[tid]; rowstart[d] = gs + ex; }
    }
    __syncthreads();
    for (int i = tid; i < sz; i += 256) {
        int v = bucketed[gs + i];
        int d7 = v >> 17;
        int r = atomicAdd(&cur[d7], 1);
        srcs[gs + lb[d7] + r] = v & 0x1FFFF;
    }
}

// ---------------- Layer-1 aggregation ------------------------------------------
// Round-16: 16-slot iteration. Phase A: lane (t=j&15, q=j>>4) loads slot t's
// src + a_s float2 (heads 2q,2q+1), 2 __expf, stages 128 weights in 512B LDS.
// Phase B (same lane decomposition, reused as feature-quad t / edge-group q):
// 4 bpermutes + 4 LDS weight reads + 4 float4 gathers + 16 FMA; den free-rides
// on the same xor16/32 merge as acc (explicit denom reduce deleted). Whole
// invalid edge-groups are skipped -> tail row-0 gathers drop 41% -> <=3/node.
__global__ __launch_bounds__(256) void k_agg1(
    const int* __restrict__ deg, const int* __restrict__ rowstart,
    const int* __restrict__ srcs,
    const float* __restrict__ a_s, const float* __restrict__ a_d,
    const float* __restrict__ h1, const float* __restrict__ b1,
    float* __restrict__ x, int N)
{
    __shared__ float sex[4][128];
    const int tid = threadIdx.x, w = tid >> 6, j = tid & 63;
    const int t = j & 15, q = j >> 4;
    const int n = blockIdx.x * 4 + w;
    if (n >= N) return;
    const int rlen = deg[n];
    const int row = rowstart[n];
    const float2 ad2 = *(const float2*)&a_d[n * NHEAD + 2 * q];
    const int h = t >> 1;
    float* sw = sex[w];
    float4 acc = {0.f, 0.f, 0.f, 0.f};
    float den = 0.f;
    // preload iteration 0
    bool v = (t < rlen);
    int   s  = v ? srcs[row + t] : 0;
    float2 a2 = v ? *(const float2*)&a_s[s * NHEAD + 2 * q] : make_float2(0.f, 0.f);
    for (int base = 0; base < rlen; base += 16) {
        // prefetch next iteration's src + a_s (overlaps exp + gathers below)
        bool vn = (base + 16 + t < rlen);
        int   sn  = vn ? srcs[row + base + 16 + t] : 0;
        float2 an = vn ? *(const float2*)&a_s[sn * NHEAD + 2 * q] : make_float2(0.f, 0.f);
        float e0 = 0.f, e1 = 0.f;
        if (v) {
            float x0 = a2.x + ad2.x; x0 = x0 > 0.f ? x0 : NEG * x0; e0 = __expf(x0);
            float x1 = a2.y + ad2.y; x1 = x1 > 0.f ? x1 : NEG * x1; e1 = __expf(x1);
        }
        *(float2*)&sw[t * 8 + 2 * q] = make_float2(e0, e1);
        asm volatile("s_waitcnt lgkmcnt(0)" ::: "memory");
        int mTot = rlen - base;
        if (4 * q < mTot) {
            int s0 = __shfl(s, 4 * q + 0), s1 = __shfl(s, 4 * q + 1);
            int s2 = __shfl(s, 4 * q + 2), s3 = __shfl(s, 4 * q + 3);
            float w0 = sw[(4 * q + 0) * 8 + h], w1 = sw[(4 * q + 1) * 8 + h];
            float w2 = sw[(4 * q + 2) * 8 + h], w3 = sw[(4 * q + 3) * 8 + h];
            float4 l0 = *(const float4*)&h1[(size_t)s0 * D1 + 4 * t];
            float4 l1 = *(const float4*)&h1[(size_t)s1 * D1 + 4 * t];
            float4 l2 = *(const float4*)&h1[(size_t)s2 * D1 + 4 * t];
            float4 l3 = *(const float4*)&h1[(size_t)s3 * D1 + 4 * t];
            fma4(acc, w0, l0); fma4(acc, w1, l1);
            fma4(acc, w2, l2); fma4(acc, w3, l3);
            den += (w0 + w1) + (w2 + w3);
        }
        asm volatile("s_waitcnt lgkmcnt(0)" ::: "memory");  // reads drain before rewrite
        v = vn; s = sn; a2 = an;
    }
    // merge the 4 q-replicas (den rides along)
    acc.x += __shfl_xor(acc.x, 16); acc.y += __shfl_xor(acc.y, 16);
    acc.z += __shfl_xor(acc.z, 16); acc.w += __shfl_xor(acc.w, 16);
    den   += __shfl_xor(den, 16);
    acc.x += __shfl_xor(acc.x, 32); acc.y += __shfl_xor(acc.y, 32);
    acc.z += __shfl_xor(acc.z, 32); acc.w += __shfl_xor(acc.w, 32);
    den   += __shfl_xor(den, 32);
    if (q == 0) {
        float4 b = *(const float4*)&b1[4 * t];
        float4 o;
        o.x = acc.x / den + b.x; o.y = acc.y / den + b.y;
        o.z = acc.z / den + b.z; o.w = acc.w / den + b.w;
        o.x = o.x > 0.f ? o.x : expm1f(o.x);
        o.y = o.y > 0.f ? o.y : expm1f(o.y);
        o.z = o.z > 0.f ? o.z : expm1f(o.z);
        o.w = o.w > 0.f ? o.w : expm1f(o.w);
        *(float4*)&x[(size_t)n * D1 + 4 * t] = o;
    }
}

// ---------------- Kernel D: h2 = x @ W2, a_src2/a_dst2 (4x4 register tile) ----------------
__global__ __launch_bounds__(256) void k_gemm2(
    const float* __restrict__ x,
    const float* __restrict__ W2,
    const float* __restrict__ att_s,
    const float* __restrict__ att_d,
    float* __restrict__ h2, float* __restrict__ a_src, float* __restrict__ a_dst,
    int N)
{
    __shared__ float Wh[64 * 64];
    __shared__ float Fh[64 * 68];
    const int tid = threadIdx.x;
    const int tx = tid & 15, ty = tid >> 4;
    const int base = blockIdx.x * 64;
    for (int i = tid; i < 64 * 64; i += 256)
        Wh[i] = W2[i];
    for (int i = tid; i < 64 * 64; i += 256) {
        int r = i >> 6, kk = i & 63;
        int n = base + r;
        Fh[r * 68 + kk] = (n < N) ? x[(size_t)n * 64 + kk] : 0.f;
    }
    __syncthreads();
    float4 acc0 = {0,0,0,0}, acc1 = {0,0,0,0}, acc2 = {0,0,0,0}, acc3 = {0,0,0,0};
    const float* wk = &Wh[4 * tx];
    const float* f0 = &Fh[(4 * ty + 0) * 68];
    const float* f1 = &Fh[(4 * ty + 1) * 68];
    const float* f2 = &Fh[(4 * ty + 2) * 68];
    const float* f3 = &Fh[(4 * ty + 3) * 68];
    #pragma unroll 4
    for (int kk = 0; kk < 64; kk += 4) {
        float4 fa = *(const float4*)&f0[kk];
        float4 fb = *(const float4*)&f1[kk];
        float4 fc = *(const float4*)&f2[kk];
        float4 fd = *(const float4*)&f3[kk];
        float4 w0 = *(const float4*)&wk[(kk + 0) * 64];
        float4 w1 = *(const float4*)&wk[(kk + 1) * 64];
        float4 w2 = *(const float4*)&wk[(kk + 2) * 64];
        float4 w3 = *(const float4*)&wk[(kk + 3) * 64];
        fma4(acc0, fa.x, w0); fma4(acc0, fa.y, w1); fma4(acc0, fa.z, w2); fma4(acc0, fa.w, w3);
        fma4(acc1, fb.x, w0); fma4(acc1, fb.y, w1); fma4(acc1, fb.z, w2); fma4(acc1, fb.w, w3);
        fma4(acc2, fc.x, w0); fma4(acc2, fc.y, w1); fma4(acc2, fc.z, w2); fma4(acc2, fc.w, w3);
        fma4(acc3, fd.x, w0); fma4(acc3, fd.y, w1); fma4(acc3, fd.z, w2); fma4(acc3, fd.w, w3);
    }
    const float4 as4 = *(const float4*)&att_s[4 * tx];
    const float4 ad4 = *(const float4*)&att_d[4 * tx];
    float4 accs[4] = {acc0, acc1, acc2, acc3};
    #pragma unroll
    for (int i = 0; i < 4; ++i) {
        int n = base + 4 * ty + i;
        if (n < N) {
            *(float4*)&h2[(size_t)n * 64 + 4 * tx] = accs[i];
            float ps = accs[i].x * as4.x + accs[i].y * as4.y + accs[i].z * as4.z + accs[i].w * as4.w;
            float pd = accs[i].x * ad4.x + accs[i].y * ad4.y + accs[i].z * ad4.z + accs[i].w * ad4.w;
            ps += __shfl_xor(ps, 1); pd += __shfl_xor(pd, 1);
            ps += __shfl_xor(ps, 2); pd += __shfl_xor(pd, 2);
            ps += __shfl_xor(ps, 4); pd += __shfl_xor(pd, 4);
            ps += __shfl_xor(ps, 8); pd += __shfl_xor(pd, 8);
            if (tx == 0) { a_src[n] = ps; a_dst[n] = pd; }
        }
    }
}

// ---------------- Layer-2 aggregation + bias + log-softmax + argmax + NLL ------
// 4 nodes per wave (16 lanes each); per-edge (src, ex) staged in LDS.
__global__ __launch_bounds__(256) void k_agg2(
    const int* __restrict__ deg, const int* __restrict__ rowstart,
    const int* __restrict__ srcs,
    const float* __restrict__ a_s, const float* __restrict__ a_d,
    const float* __restrict__ h2, const float* __restrict__ b2,
    const int* __restrict__ label,
    float* __restrict__ dout, double* __restrict__ bins, int N)
{
    __shared__ int2 sx[4][64];
    __shared__ float snll[16];
    const int tid = threadIdx.x, w = tid >> 6, j = tid & 63;
    const int t = j & 15, g16 = j & 0x30;  // node's 16-lane group base within wave
    const int n = blockIdx.x * 16 + (tid >> 4);
    if (tid < 16) snll[tid] = 0.f;
    __syncthreads();
    const bool valid = (n < N);
    const int rlen = valid ? deg[n] : 0;
    const int row  = valid ? rowstart[n] : 0;
    const float ad = valid ? a_d[n] : 0.f;
    float4 acc = {0.f, 0.f, 0.f, 0.f};
    float den = 0.f;
    for (int base = 0; base < rlen; base += 16) {
        int m = rlen - base; if (m > 16) m = 16;
        int myS = 0; float ex = 0.f;
        if (t < m) {
            myS = srcs[row + base + t];
            float v = a_s[myS] + ad;
            v = v > 0.f ? v : NEG * v;
            ex = __expf(v);
        }
        float ds = ex;
        ds += __shfl_xor(ds, 1); ds += __shfl_xor(ds, 2);
        ds += __shfl_xor(ds, 4); ds += __shfl_xor(ds, 8);
        den += ds;
        sx[w][j] = make_int2(myS, __float_as_int(ex));
        asm volatile("s_waitcnt lgkmcnt(0)" ::: "memory");
        for (int kb = 0; kb < m; kb += 4) {            // kb in {0,4,8,12}: idx <= 15
            int2 p0 = sx[w][g16 | (kb + 0)];
            int2 p1 = sx[w][g16 | (kb + 1)];
            int2 p2 = sx[w][g16 | (kb + 2)];
            int2 p3 = sx[w][g16 | (kb + 3)];
            float4 l0 = *(const float4*)&h2[(size_t)p0.x * 64 + 4 * t];
            float4 l1 = *(const float4*)&h2[(size_t)p1.x * 64 + 4 * t];
            float4 l2 = *(const float4*)&h2[(size_t)p2.x * 64 + 4 * t];
            float4 l3 = *(const float4*)&h2[(size_t)p3.x * 64 + 4 * t];
            fma4(acc, __int_as_float(p0.y), l0);
            fma4(acc, __int_as_float(p1.y), l1);
            fma4(acc, __int_as_float(p2.y), l2);
            fma4(acc, __int_as_float(p3.y), l3);
        }
        asm volatile("s_waitcnt lgkmcnt(0)" ::: "memory");  // reads drain before rewrite
    }
    float4 b = *(const float4*)&b2[4 * t];
    float4 sc;
    sc.x = acc.x / den + b.x; sc.y = acc.y / den + b.y;
    sc.z = acc.z / den + b.z; sc.w = acc.w / den + b.w;
    float mv = sc.x; int mi = 4 * t;
    if (sc.y > mv) { mv = sc.y; mi = 4 * t + 1; }
    if (sc.z > mv) { mv = sc.z; mi = 4 * t + 2; }
    if (sc.w > mv) { mv = sc.w; mi = 4 * t + 3; }
    #pragma unroll
    for (int off = 1; off < 16; off <<= 1) {
        float ov = __shfl_xor(mv, off);
        int oi = __shfl_xor(mi, off);
        if (ov > mv || (ov == mv && oi < mi)) { mv = ov; mi = oi; }
    }
    float se = __expf(sc.x - mv) + __expf(sc.y - mv) + __expf(sc.z - mv) + __expf(sc.w - mv);
    #pragma unroll
    for (int off = 1; off < 16; off <<= 1) se += __shfl_xor(se, off);
    int lab = valid ? label[n] : 0;
    int comp = lab & 3;
    float cl = comp == 0 ? sc.x : comp == 1 ? sc.y : comp == 2 ? sc.z : sc.w;
    float sl = __shfl(cl, g16 | (lab >> 2));
    if (t == 0 && valid) {
        snll[tid >> 4] = mv + logf(se) - sl;
        dout[1 + n] = (float)mi;
        dout[1 + (size_t)N + n] = (float)lab;
    }
    __syncthreads();
    if (tid == 0) {
        double bs = 0.0;
        #pragma unroll
        for (int i = 0; i < 16; ++i) bs += (double)snll[i];
        atomicAdd(&bins[blockIdx.x & (NBINS - 1)], bs);
    }
}

// Single block of 256: reduce NBINS doubles -> loss
__global__ __launch_bounds__(256) void k_loss(
    const double* __restrict__ bins, float* __restrict__ dout, int N)
{
    __shared__ double sw[4];
    const int tid = threadIdx.x;
    double v = bins[tid];
    #pragma unroll
    for (int off = 1; off < 64; off <<= 1) v += __shfl_xor(v, off);
    if ((tid & 63) == 0) sw[tid >> 6] = v;
    __syncthreads();
    if (tid == 0)
        dout[0] = (float)((sw[0] + sw[1] + sw[2] + sw[3]) / (double)N);
}

extern "C" void kernel_launch(void* const* d_in, const int* in_sizes, int n_in,
                              void* d_out, int out_size, void* d_ws, size_t ws_size,
                              hipStream_t stream)
{
    const float* feat   = (const float*)d_in[1];
    const int*   edge   = (const int*)d_in[2];
    const int*   label  = (const int*)d_in[4];
    const float* W1     = (const float*)d_in[5];
    const float* att_s1 = (const float*)d_in[6];
    const float* att_d1 = (const float*)d_in[7];
    const float* b1     = (const float*)d_in[8];
    const float* W2     = (const float*)d_in[9];
    const float* att_s2 = (const float*)d_in[10];
    const float* att_d2 = (const float*)d_in[11];
    const float* b2     = (const float*)d_in[12];

    const int N = in_sizes[0];
    const int E = in_sizes[2] / 2;
    const int* src = edge;
    const int* dst = edge + E;

    // workspace layout:
    float* bufA = (float*)d_ws;               // N*64: h1 / h2 (no aliases)
    float* bufB = bufA + (size_t)N * 64;      // N*64: x; aliases CSR-build scratch
    float* a_s1 = bufB + (size_t)N * 64;      // N*8 (layer2: a_s2=[0..N), a_d2=[N..2N))
    float* a_d1 = a_s1 + (size_t)N * 8;       // N*8
    int*   deg  = (int*)(a_d1 + (size_t)N * 8); // N
    int*   rowstart = deg + N;                // N (absolute CSR row starts)
    int*   srcs = rowstart + N;               // E
    double* bins = (double*)(((uintptr_t)(srcs + E) + 7) & ~(uintptr_t)7);

    // Aliases in bufB — all dead before k_agg1 writes x:
    int* bucketed = (int*)bufB;               // E   packed (dst&127)<<17 | src
    int* btot  = bucketed + E;                // BINS*16 (padded: 1 counter / 64B line)
    int* gcur  = btot + BINS * 16;            // BINS*16 (padded cursors)
    int* bbase = gcur + BINS * 16;            // BINS
    int* bh    = bbase + BINS;                // GH*BINS per-block histograms

    float* a_s2 = a_s1;
    float* a_d2 = a_s1 + N;

    float* out = (float*)d_out;

    const int GH    = (E + CHUNK - 1) / CHUNK;
    const int G1    = (N + 63) / 64;
    const int NBUCK = (N + 127) / 128;

    hipMemsetAsync(btot, 0, (size_t)BINS * 16 * sizeof(int), stream);

    // bucket-hist (LDS atomics) overlapped with gemm1; then bucket scan; then
    // scatter into buckets; then per-bucket sort -> deg/rowstart/srcs.
    k_gemm1_hist<<<GH + G1, 256, 0, stream>>>(feat, W1, att_s1, att_d1,
                                              bufA, a_s1, a_d1,
                                              dst, btot, bh, N, E, GH);
    k_bscan  <<<1, 256, 0, stream>>>(btot, bbase, gcur, bins);
    k_scatter<<<GH, 256, 0, stream>>>(src, dst, bh, gcur, bucketed, E);
    k_seg    <<<NBUCK, 256, 0, stream>>>(btot, bbase, bucketed, deg, rowstart, srcs, N);

    k_agg1 <<<(N + 3) / 4, 256, 0, stream>>>(deg, rowstart, srcs, a_s1, a_d1,
                                             bufA, b1, bufB, N);
    k_gemm2<<<G1, 256, 0, stream>>>(bufB, W2, att_s2, att_d2, bufA, a_s2, a_d2, N);
    k_agg2 <<<(N + 15) / 16, 256, 0, stream>>>(deg, rowstart, srcs, a_s2, a_d2,
                                               bufA, b2, label, out, bins, N);
    k_loss <<<1, 256, 0, stream>>>(bins, out, N);
}